// Round 6
// baseline (292.644 us; speedup 1.0000x reference)
//
#include <hip/hip_runtime.h>
#include <hip/hip_bf16.h>

#define EPS 1e-5f

typedef __attribute__((ext_vector_type(8))) short bf16x8;
typedef __attribute__((ext_vector_type(4))) short bf16x4;
typedef __attribute__((ext_vector_type(4))) float f32x4;

__device__ __forceinline__ f32x4 mfma_bf16(bf16x8 a, bf16x8 b, f32x4 c) {
    return __builtin_amdgcn_mfma_f32_16x16x32_bf16(a, b, c, 0, 0, 0);
}

__device__ __forceinline__ void async_ld16(const void* g, void* l) {
    __builtin_amdgcn_global_load_lds(
        (const __attribute__((address_space(1))) void*)g,
        (__attribute__((address_space(3))) void*)l, 16, 0, 0);
}

// fast gelu: 0.5v(1+tanh z) == v * sigmoid(2z); one v_exp + one rcp.
__device__ __forceinline__ float fast_gelu(float v) {
    float z2 = 1.5957691216057308f * (v + 0.044715f * v * v * v);
    float e = __expf(z2);
    return v * e / (e + 1.f);
}

__device__ __forceinline__ float bf2f(short s) {
    union { float f; unsigned u; } v;
    v.u = ((unsigned)(unsigned short)s) << 16;
    return v.f;
}

// ---------------- merged pre-work: f32->bf16 weight convert (blocks 0..27647)
// + adaLN modulation mods[b][i] = c[b].adaLN_w[i] + adaLN_b[i] (last 36 blocks)
__global__ void k_pre(const float* __restrict__ a, __hip_bfloat16* __restrict__ oa, int na,
                      const float* __restrict__ b, __hip_bfloat16* __restrict__ ob, int nb,
                      const float* __restrict__ c, __hip_bfloat16* __restrict__ oc, int nc,
                      const float* __restrict__ d, __hip_bfloat16* __restrict__ od, int nd,
                      const float* __restrict__ cond, const float* __restrict__ alw,
                      const float* __restrict__ alb, float* __restrict__ mods) {
    if (blockIdx.x >= 27648) {
        int i = (blockIdx.x - 27648) * 256 + threadIdx.x;   // 0..9215
        int bb = i / 4608, row = i - bb * 4608;
        const float4* cv = (const float4*)(cond + bb * 128);
        const float4* wv = (const float4*)(alw + (long)row * 128);
        float acc = 0.f;
#pragma unroll
        for (int k = 0; k < 32; ++k) {
            float4 x = cv[k], y = wv[k];
            acc += x.x * y.x + x.y * y.y + x.z * y.z + x.w * y.w;
        }
        mods[i] = acc + alb[row];
        return;
    }
    int i = blockIdx.x * 256 + threadIdx.x;
    if (i < na) { oa[i] = __float2bfloat16(a[i]); return; }
    i -= na;
    if (i < nb) { ob[i] = __float2bfloat16(b[i]); return; }
    i -= nb;
    if (i < nc) { oc[i] = __float2bfloat16(c[i]); return; }
    i -= nc;
    if (i < nd) od[i] = __float2bfloat16(d[i]);
}

// ---------------- fused LayerNorm + adaLN modulate, 1 wave per token
__global__ void k_ln_mod(const float* __restrict__ x, const float* __restrict__ w,
                         const float* __restrict__ mods, int shiftOff, int scaleOff,
                         __hip_bfloat16* __restrict__ out) {
    int token = blockIdx.x;      // 0..4095
    int lane = threadIdx.x;      // 0..63
    const float4* xr = (const float4*)(x + (long)token * 768);
    float4 v0 = xr[lane], v1 = xr[lane + 64], v2 = xr[lane + 128];
    float s  = v0.x + v0.y + v0.z + v0.w + v1.x + v1.y + v1.z + v1.w + v2.x + v2.y + v2.z + v2.w;
    float ss = v0.x*v0.x + v0.y*v0.y + v0.z*v0.z + v0.w*v0.w
             + v1.x*v1.x + v1.y*v1.y + v1.z*v1.z + v1.w*v1.w
             + v2.x*v2.x + v2.y*v2.y + v2.z*v2.z + v2.w*v2.w;
#pragma unroll
    for (int m = 32; m >= 1; m >>= 1) { s += __shfl_xor(s, m); ss += __shfl_xor(ss, m); }
    float mu = s * (1.f / 768.f);
    float var = ss * (1.f / 768.f) - mu * mu;
    float rs = rsqrtf(var + EPS);
    int b = token >> 11;
    const float* sh = mods + b * 4608 + shiftOff;
    const float* sc = mods + b * 4608 + scaleOff;
    __hip_bfloat16* o = out + (long)token * 768;
    float4 vv[3] = {v0, v1, v2};
#pragma unroll
    for (int kk = 0; kk < 3; ++kk) {
        int cbase = (lane + 64 * kk) * 4;
        const float* p = (const float*)&vv[kk];
#pragma unroll
        for (int j = 0; j < 4; ++j) {
            int col = cbase + j;
            float hv = (p[j] - mu) * rs * w[col] * (1.f + sc[col]) + sh[col];
            o[col] = __float2bfloat16(hv);
        }
    }
}

// ---------------- split-K reduce + mlp2 epilogue:
// out = x2 + gate*(p0 + p1 + bias), 4 cols per thread, all f32x4-vectorized.
__global__ void k_red(const __hip_bfloat16* __restrict__ p, const float* __restrict__ x2,
                      const float* __restrict__ mods, const float* __restrict__ bias,
                      float* __restrict__ out) {
    long base = ((long)blockIdx.x * 256 + threadIdx.x) * 4;    // 0..3145724
    int col = (int)(base % 768);
    int row = (int)(base / 768);
    int b = row >> 11;
    short4 a0 = *(const short4*)(p + base);
    short4 a1 = *(const short4*)(p + 3145728 + base);
    float4 xr = *(const float4*)(x2 + base);
    float4 gt = *(const float4*)(mods + b * 4608 + 3840 + col);
    float4 bs = *(const float4*)(bias + col);
    float4 o;
    o.x = xr.x + gt.x * (bf2f(a0.x) + bf2f(a1.x) + bs.x);
    o.y = xr.y + gt.y * (bf2f(a0.y) + bf2f(a1.y) + bs.y);
    o.z = xr.z + gt.z * (bf2f(a0.z) + bf2f(a1.z) + bs.z);
    o.w = xr.w + gt.w * (bf2f(a0.w) + bf2f(a1.w) + bs.w);
    *(float4*)(out + base) = o;
}

// ---------------- block-sparse flash attention, no-max softmax.
// R18 (counters): coalesced LDS staging of K/V (shared across 4 waves per
// workgroup) cut the scattered-gather txn count ~10x -> 56 -> ~36us.
// R19: remaining gap vs the ~17-20us issue floor = exposed LDS round-trip
// in the per-chunk chain: exp -> 16 ds_write -> lgkm(0) -> 4 ds_read ->
// lgkm(0) -> PV, two full drains with nothing under them (occupancy is
// LDS-capped at 3 blocks/CU so TLP can't cover). Fix: deferred-PV software
// pipeline -- keep prev chunk's pa/vf fragments in registers and issue its
// 8 PV MFMAs BETWEEN this chunk's P-writes and the drain (drain hides under
// MFMA exec); second drain removed (pa consumed next iter; compiler emits
// counted lgkmcnt). VGPR +~12 is free (LDS-bound occupancy up to ~168).
// s_setprio(1) around MFMA clusters (T5: +4-7% attn, m191).
// Structure: workgroup = 4 q-blocks sharing a prefix, w=0..3 <->
// (fl,blk) in {(0,b0),(1,b0),(0,b0+1),(1,b0+1)}; K/V chunks staged via
// coalesced global_load_lds (dbuf, vmcnt(4) counted), XOR-swizzled via
// pre-swizzled GLOBAL source (LDS dest linear, m104/m173); conflict-free
// ds_read_b128 fragments. Per-wave act masks; tail subtiles masked p=0.
__global__ __launch_bounds__(256) void k_attn(
    const __hip_bfloat16* __restrict__ q, const __hip_bfloat16* __restrict__ k,
    const __hip_bfloat16* __restrict__ vT, __hip_bfloat16* __restrict__ out) {
    __shared__ __hip_bfloat16 KL[2][64 * 64];   // [buf][key(64)][dim(64)] swizzled
    __shared__ __hip_bfloat16 VL[2][64 * 64];   // [buf][dim(64)][lkey(64)] swizzled
    __shared__ __hip_bfloat16 P[4][16 * 68];    // per-wave P tile
    int tid = threadIdx.x;
    int w = tid >> 6, lane = tid & 63, l15 = lane & 15, quad = lane >> 4;
    int idx = blockIdx.x;                  // 0..767
    int bh = idx % 24;                     // fastest: spreads across XCDs
    int gi = idx / 24;                     // 0..31
    int b0 = 62 - 2 * gi;                  // longest prefix first
    int fl = w & 1, blk = b0 + (w >> 1);
    int qblk = fl * 64 + blk;

    const __hip_bfloat16* Q = q + ((long)bh * 2048 + qblk * 16) * 64;
    bf16x8 qa = *(const bf16x8*)(Q + l15 * 64 + quad * 8);
    bf16x8 qb = *(const bf16x8*)(Q + l15 * 64 + 32 + quad * 8);
    const __hip_bfloat16* K = k + (long)bh * 2048 * 64;
    const __hip_bfloat16* V = vT + (long)bh * 64 * 2048;

    // staged subtile t -> global key base (clamped to 0 when out of range)
    auto kbase = [&](int t) -> int {
        if (t < b0 + 2) return 1024 + t * 16;
        if (t == b0 + 2) return b0 * 16;
        if (t == b0 + 3) return (b0 + 1) * 16;
        return 0;
    };
    // per-wave subtile activity (wave-uniform)
    auto active = [&](int t) -> bool {
        if (w == 0) return t < b0 || t == b0 + 2;
        if (w == 1) return t < b0 + 1;
        if (w == 2) return t < b0 + 1 || t == b0 + 3;
        return t < b0 + 2;
    };

    // staging decode constants (per thread: 2 K instrs + 2 V instrs)
    // K LDS linear offset o -> row kk=o>>7, byte b=o&127; source byte in row
    // = b ^ ((kk&7)<<4) (XOR involution => read-side uses the same XOR).
    // V LDS: row d=o>>7 (dim), local-key bytes lk2 = b ^ ((d&7)<<4).
    int kkr[2], kbs[2], vsi[2], vki[2];
#pragma unroll
    for (int i = 0; i < 2; ++i) {
        int o = i * 4096 + tid * 16;
        kkr[i] = o >> 7;
        int b = o & 127;
        kbs[i] = b ^ ((kkr[i] & 7) << 4);
        int lk2 = b ^ ((kkr[i] & 7) << 4);   // same row index for V decode
        vsi[i] = lk2 >> 5;
        vki[i] = (lk2 & 31) >> 1;
    }
    auto stage = [&](int ci, int buf) {
#pragma unroll
        for (int i = 0; i < 2; ++i) {
            int gk = kbase(4 * ci + (kkr[i] >> 4)) + (kkr[i] & 15);
            async_ld16(K + (long)gk * 64 + (kbs[i] >> 1),
                       (char*)&KL[buf][0] + i * 4096 + tid * 16);
        }
#pragma unroll
        for (int i = 0; i < 2; ++i) {
            int gk = kbase(4 * ci + vsi[i]) + vki[i];
            async_ld16(V + (long)kkr[i] * 2048 + gk,
                       (char*)&VL[buf][0] + i * 4096 + tid * 16);
        }
    };

    // fragment LDS offsets (shorts), swizzle matches staging
    int kfo[4][2], vfo[2][4];
#pragma unroll
    for (int s = 0; s < 4; ++s)
#pragma unroll
        for (int h = 0; h < 2; ++h)
            kfo[s][h] = (s * 16 + l15) * 64 +
                        (((h * 64 + quad * 16) ^ ((l15 & 7) << 4)) >> 1);
#pragma unroll
    for (int p2 = 0; p2 < 2; ++p2)
#pragma unroll
        for (int tt = 0; tt < 4; ++tt) {
            int d = tt * 16 + l15;
            int c = (p2 * 64 + (quad >> 1) * 32 + (quad & 1) * 16) ^ ((l15 & 7) << 4);
            vfo[p2][tt] = d * 64 + (c >> 1);
        }

    const f32x4 vzero = {0.f, 0.f, 0.f, 0.f};
    f32x4 o[4]; float l[4];
#pragma unroll
    for (int rr = 0; rr < 4; ++rr) { o[rr] = vzero; l[rr] = 0.f; }

    int nIter = (b0 + 7) >> 2;             // T = b0+4 staged subtiles
    __hip_bfloat16* Pw = &P[w][0];

    bf16x8 paP[2];          // prev-chunk P fragments (deferred PV)
    bf16x8 vfP[2][4];       // prev-chunk V fragments

    stage(0, 0);
    for (int ci = 0; ci < nIter; ++ci) {
        int cb = ci & 1;
        if (ci > 0) asm volatile("s_barrier" ::: "memory");      // buf cb^1 free
        if (ci + 1 < nIter) {
            stage(ci + 1, cb ^ 1);
            asm volatile("s_waitcnt vmcnt(4)" ::: "memory");     // chunk ci landed
        } else {
            asm volatile("s_waitcnt vmcnt(0)" ::: "memory");
        }
        asm volatile("s_barrier" ::: "memory");                  // chunk ci visible

        bf16x8 ka[4], kb8[4];
#pragma unroll
        for (int s = 0; s < 4; ++s) {
            ka[s]  = *(const bf16x8*)&KL[cb][kfo[s][0]];
            kb8[s] = *(const bf16x8*)&KL[cb][kfo[s][1]];
        }
        // scores: D[m=q][n=key]; lane: col=key=l15, row q=quad*4+rr
        f32x4 sc[4];
        __builtin_amdgcn_s_setprio(1);
#pragma unroll
        for (int s = 0; s < 4; ++s)
            sc[s] = mfma_bf16(qb, kb8[s], mfma_bf16(qa, ka[s], vzero));
        __builtin_amdgcn_s_setprio(0);
        bf16x8 vf[2][4];
#pragma unroll
        for (int p2 = 0; p2 < 2; ++p2)
#pragma unroll
            for (int tt = 0; tt < 4; ++tt)
                vf[p2][tt] = *(const bf16x8*)&VL[cb][vfo[p2][tt]];

        // exp + mask, accumulate l, write P[q][64 keys] (stride 68)
#pragma unroll
        for (int s = 0; s < 4; ++s) {
            bool a = active(4 * ci + s);
#pragma unroll
            for (int rr = 0; rr < 4; ++rr) {
                float pv = a ? __expf(sc[s][rr]) : 0.f;
                l[rr] += pv;
                Pw[(quad * 4 + rr) * 68 + s * 16 + l15] = __float2bfloat16(pv);
            }
        }
        // deferred PV of chunk ci-1: pure-register MFMAs execute while the
        // P(ci) writes drain -- hides the LDS round-trip latency.
        if (ci > 0) {
            __builtin_amdgcn_s_setprio(1);
#pragma unroll
            for (int p2 = 0; p2 < 2; ++p2)
#pragma unroll
                for (int tt = 0; tt < 4; ++tt)
                    o[tt] = mfma_bf16(paP[p2], vfP[p2][tt], o[tt]);
            __builtin_amdgcn_s_setprio(0);
        }
        asm volatile("s_waitcnt lgkmcnt(0)" ::: "memory");       // P(ci) visible
        bf16x8 pa[2];
#pragma unroll
        for (int p2 = 0; p2 < 2; ++p2) {
            union { bf16x4 h[2]; bf16x8 v; } u;
            u.h[0] = *(const bf16x4*)(Pw + l15 * 68 + p2 * 32 + quad * 8);
            u.h[1] = *(const bf16x4*)(Pw + l15 * 68 + p2 * 32 + quad * 8 + 4);
            pa[p2] = u.v;
        }
        // no drain: pa consumed next iteration (compiler emits counted wait)
#pragma unroll
        for (int p2 = 0; p2 < 2; ++p2) {
            paP[p2] = pa[p2];
#pragma unroll
            for (int tt = 0; tt < 4; ++tt) vfP[p2][tt] = vf[p2][tt];
        }
    }
    // final PV for the last chunk
    asm volatile("s_waitcnt lgkmcnt(0)" ::: "memory");
    __builtin_amdgcn_s_setprio(1);
#pragma unroll
    for (int p2 = 0; p2 < 2; ++p2)
#pragma unroll
        for (int tt = 0; tt < 4; ++tt)
            o[tt] = mfma_bf16(paP[p2], vfP[p2][tt], o[tt]);
    __builtin_amdgcn_s_setprio(0);

    // epilogue: per-wave, direct write (no merge needed)
    int b = bh / 12, h = bh - b * 12;
    int seqbase = qblk * 16;
#pragma unroll
    for (int rr = 0; rr < 4; ++rr) {
        float lr = l[rr];
#pragma unroll
        for (int msk = 1; msk < 16; msk <<= 1) lr += __shfl_xor(lr, msk, 16);
        float inv = 1.f / lr;
        long row = b * 2048 + seqbase + quad * 4 + rr;
#pragma unroll
        for (int tt = 0; tt < 4; ++tt)
            out[row * 768 + h * 64 + tt * 16 + l15] = __float2bfloat16(o[tt][rr] * inv);
    }
}

// ---------------- 128xTN bf16 GEMM, 2 LDS buffers (32 KB at TN=128 ->
// 5 blocks/CU, the R8 occupancy recipe on the half-traffic 128-tile).
// Depth-1 pipeline: stage(i+1) into the opposite buffer right after the top
// barrier (safe: that barrier proves compute i-1, which read that buffer,
// is done in all waves); vmcnt(NINST) keeps tile i+1 in flight during
// compute i; 4 other resident blocks cover the residual stall.
// XOR-swizzled LDS (0 conflicts). lda = row stride; blockIdx.z*K = split-K.
// MODE 1: Cf = mods[gate]*acc + resid   (attn proj + gate + residual)
// MODE 2: Cb = bf16(fast_gelu(acc + bias))   (mlp1)
// MODE 3: Cf = resid + mods[gate]*(acc+bias)  (mlp2 + gate + residual)
// MODE 4: qkv + fused RoPE epilogue -> q (x0.125), k, vT bf16 (TN=128 only).
// MODE 5: split-K partial: Cb[z*M*N + row*N+col] = bf16(acc).
template <int MODE, int TN>
__global__ __launch_bounds__(TN == 128 ? 256 : 128) void k_gemm(
    const __hip_bfloat16* __restrict__ A, const __hip_bfloat16* __restrict__ W,
    float* __restrict__ Cf, __hip_bfloat16* __restrict__ Cb,
    const float* __restrict__ bias, const float* __restrict__ mods, int gateOff,
    const float* __restrict__ resid, const float* __restrict__ cosb,
    const float* __restrict__ sinb, __hip_bfloat16* __restrict__ qo,
    __hip_bfloat16* __restrict__ ko, __hip_bfloat16* __restrict__ vo,
    int M, int N, int K, int lda) {
    constexpr int NW = (TN == 128) ? 4 : 2;
    constexpr int ACH = 512 / (NW * 64);
    constexpr int BCH = (TN * 4) / (NW * 64);
    constexpr int NINST = ACH + BCH;
    __shared__ __hip_bfloat16 lA[2][128 * 32];
    __shared__ __hip_bfloat16 lB[2][TN * 32];
    int t = threadIdx.x;
    int wave = t >> 6, lane = t & 63, l15 = lane & 15, quad = lane >> 4;
    int wr = (TN == 128) ? (wave >> 1) : wave;
    int wc = (TN == 128) ? (wave & 1) : 0;
    int sw8 = (quad ^ ((l15 >> 1) & 3)) * 8;
    long bm = blockIdx.x, bn = blockIdx.y;
    const __hip_bfloat16* Ab = A + bm * 128 * lda + (long)blockIdx.z * K;
    const __hip_bfloat16* Wb = W + bn * TN * lda + (long)blockIdx.z * K;

    long soffA[ACH], soffB[BCH];
#pragma unroll
    for (int cc = 0; cc < ACH; ++cc) {
        int chunk = cc * NW * 64 + t;
        int row = chunk >> 2;
        int c = (chunk & 3) ^ ((row >> 1) & 3);
        soffA[cc] = (long)row * lda + c * 8;
    }
#pragma unroll
    for (int cc = 0; cc < BCH; ++cc) {
        int chunk = cc * NW * 64 + t;
        int row = chunk >> 2;
        int c = (chunk & 3) ^ ((row >> 1) & 3);
        soffB[cc] = (long)row * lda + c * 8;
    }
    auto stage = [&](int k0, int buf) {
        char* lAc = (char*)&lA[buf][0];
        char* lBc = (char*)&lB[buf][0];
#pragma unroll
        for (int cc = 0; cc < ACH; ++cc)
            async_ld16(Ab + soffA[cc] + k0, lAc + cc * (NW * 1024) + wave * 1024);
#pragma unroll
        for (int cc = 0; cc < BCH; ++cc)
            async_ld16(Wb + soffB[cc] + k0, lBc + cc * (NW * 1024) + wave * 1024);
    };

    f32x4 acc[4][4];
#pragma unroll
    for (int i = 0; i < 4; ++i)
#pragma unroll
        for (int j = 0; j < 4; ++j) acc[i][j] = (f32x4){0.f, 0.f, 0.f, 0.f};

    int nIter = K / 32;
    stage(0, 0);
    for (int i = 0; i < nIter; ++i) {
        int cb = i & 1;
        if (i > 0) asm volatile("s_barrier" ::: "memory");   // buf !cb free
        if (i + 1 < nIter) {
            stage((i + 1) * 32, cb ^ 1);
            asm volatile("s_waitcnt vmcnt(%0)" :: "n"(NINST) : "memory");  // tile i landed
        } else {
            asm volatile("s_waitcnt vmcnt(0)" ::: "memory");
        }
        asm volatile("s_barrier" ::: "memory");              // tile i visible
        bf16x8 af[4], bfr[4];
#pragma unroll
        for (int ii = 0; ii < 4; ++ii)
            af[ii] = *(const bf16x8*)&lA[cb][(wr * 64 + ii * 16 + l15) * 32 + sw8];
#pragma unroll
        for (int j = 0; j < 4; ++j)
            bfr[j] = *(const bf16x8*)&lB[cb][(wc * 64 + j * 16 + l15) * 32 + sw8];
#pragma unroll
        for (int ii = 0; ii < 4; ++ii)
#pragma unroll
            for (int j = 0; j < 4; ++j)
                acc[ii][j] = mfma_bf16(af[ii], bfr[j], acc[ii][j]);
    }

    if (MODE == 4) {
        int hcol = (int)bn * 2 + wc;               // 0..35
        int th = hcol / 12, h = hcol % 12;
#pragma unroll
        for (int i = 0; i < 4; ++i) {
#pragma unroll
            for (int r = 0; r < 4; ++r) {
                int row = (int)bm * 128 + wr * 64 + i * 16 + quad * 4 + r;
                int s = row & 2047, b = row >> 11;
                long bh_ = b * 12 + h;
                const float* cbp = cosb + s * 64;
                const float* sbp = sinb + s * 64;
#pragma unroll
                for (int j = 0; j < 2; ++j) {
                    int dh = j * 16 + l15;
                    float a0f = acc[i][j][r], a1f = acc[i][j + 2][r];
                    float o0 = a0f * cbp[dh] - a1f * sbp[dh];
                    float o1 = a1f * cbp[dh + 32] + a0f * sbp[dh + 32];
                    if (th == 0) {
                        __hip_bfloat16* d = qo + (bh_ * 2048 + s) * 64;
                        d[dh]      = __float2bfloat16(o0 * 0.125f);
                        d[dh + 32] = __float2bfloat16(o1 * 0.125f);
                    } else if (th == 1) {
                        __hip_bfloat16* d = ko + (bh_ * 2048 + s) * 64;
                        d[dh]      = __float2bfloat16(o0);
                        d[dh + 32] = __float2bfloat16(o1);
                    } else {
                        __hip_bfloat16* d = vo + bh_ * 64 * 2048 + s;
                        d[(long)dh * 2048]        = __float2bfloat16(o0);
                        d[(long)(dh + 32) * 2048] = __float2bfloat16(o1);
                    }
                }
            }
        }
        return;
    }

#pragma unroll
    for (int i = 0; i < 4; ++i) {
#pragma unroll
        for (int j = 0; j < 4; ++j) {
#pragma unroll
            for (int r = 0; r < 4; ++r) {
                int row = (int)bm * 128 + wr * 64 + i * 16 + quad * 4 + r;
                int col = (int)bn * TN + wc * 64 + j * 16 + l15;
                float v = acc[i][j][r];
                long idx = (long)row * N + col;
                if (MODE == 1) {
                    Cf[idx] = mods[(row >> 11) * 4608 + gateOff + col] * v + resid[idx];
                } else if (MODE == 2) {
                    Cb[idx] = __float2bfloat16(fast_gelu(v + bias[col]));
                } else if (MODE == 3) {
                    Cf[idx] = resid[idx] + mods[(row >> 11) * 4608 + gateOff + col] * (v + bias[col]);
                } else {   // MODE 5: split-K partial
                    Cb[(long)blockIdx.z * M * N + idx] = __float2bfloat16(v);
                }
            }
        }
    }
}

extern "C" void kernel_launch(void* const* d_in, const int* in_sizes, int n_in,
                              void* d_out, int out_size, void* d_ws, size_t ws_size,
                              hipStream_t stream) {
    const float* x    = (const float*)d_in[0];
    const float* c    = (const float*)d_in[1];
    const float* cosb = (const float*)d_in[2];
    const float* sinb = (const float*)d_in[3];
    // d_in[4] = mask: unused, computed analytically
    const float* n1w  = (const float*)d_in[5];
    const float* qkvw = (const float*)d_in[6];
    const float* aow  = (const float*)d_in[7];
    const float* n2w  = (const float*)d_in[8];
    const float* w1   = (const float*)d_in[9];
    const float* b1   = (const float*)d_in[10];
    const float* w2   = (const float*)d_in[11];
    const float* b2   = (const float*)d_in[12];
    const float* alw  = (const float*)d_in[13];
    const float* alb  = (const float*)d_in[14];

    char* ws = (char*)d_ws;
    size_t off = 0;
    auto alloc = [&](size_t bytes) -> void* {
        void* p = ws + off;
        off += (bytes + 255) & ~(size_t)255;
        return p;
    };
    float*          mods = (float*)alloc(2 * 4608 * 4);
    __hip_bfloat16* hbuf = (__hip_bfloat16*)alloc((size_t)4096 * 768 * 2);
    __hip_bfloat16* qb   = (__hip_bfloat16*)alloc((size_t)24 * 2048 * 64 * 2);
    __hip_bfloat16* kb   = (__hip_bfloat16*)alloc((size_t)24 * 2048 * 64 * 2);
    __hip_bfloat16* vT   = (__hip_bfloat16*)alloc((size_t)24 * 64 * 2048 * 2);
    __hip_bfloat16* abuf = (__hip_bfloat16*)alloc((size_t)4096 * 768 * 2);
    float*          x2   = (float*)alloc((size_t)4096 * 768 * 4);
    __hip_bfloat16* h2   = (__hip_bfloat16*)alloc((size_t)4096 * 768 * 2);
    __hip_bfloat16* m1   = (__hip_bfloat16*)alloc((size_t)4096 * 3072 * 2);
    __hip_bfloat16* m2p  = (__hip_bfloat16*)alloc((size_t)2 * 4096 * 768 * 2);
    __hip_bfloat16* wq   = (__hip_bfloat16*)alloc((size_t)2304 * 768 * 2);
    __hip_bfloat16* wa   = (__hip_bfloat16*)alloc((size_t)768 * 768 * 2);
    __hip_bfloat16* w1b  = (__hip_bfloat16*)alloc((size_t)3072 * 768 * 2);
    __hip_bfloat16* w2b  = (__hip_bfloat16*)alloc((size_t)768 * 3072 * 2);

    k_pre<<<27684, 256, 0, stream>>>(qkvw, wq, 2304 * 768, aow, wa, 768 * 768,
                                     w1, w1b, 3072 * 768, w2, w2b, 768 * 3072,
                                     c, alw, alb, mods);
    k_ln_mod<<<4096, 64, 0, stream>>>(x, n1w, mods, 0, 768, hbuf);
    // qkv GEMM + fused RoPE -> q, k, vT
    k_gemm<4, 128><<<dim3(32, 18), 256, 0, stream>>>(hbuf, wq, nullptr, nullptr, nullptr, nullptr, 0,
                                                     nullptr, cosb, sinb, qb, kb, vT,
                                                     4096, 2304, 768, 768);
    k_attn<<<768, 256, 0, stream>>>(qb, kb, vT, abuf);
    k_gemm<1, 64><<<dim3(32, 12), 128, 0, stream>>>(abuf, wa, x2, nullptr, nullptr, mods, 1536,
                                                    x, nullptr, nullptr, nullptr, nullptr, nullptr,
                                                    4096, 768, 768, 768);
    k_ln_mod<<<4096, 64, 0, stream>>>(x2, n2w, mods, 2304, 3072, h2);
    // mlp1: 128x128 2-buffer (5 blocks/CU, half the 64-tile traffic)
    k_gemm<2, 128><<<dim3(32, 24), 256, 0, stream>>>(h2, w1b, nullptr, m1, b1, nullptr, 0,
                                                     nullptr, nullptr, nullptr, nullptr, nullptr, nullptr,
                                                     4096, 3072, 768, 768);
    // mlp2: split-K=2, 128x128 tile (low traffic) + 384 blocks (parallelism)
    k_gemm<5, 128><<<dim3(32, 6, 2), 256, 0, stream>>>(m1, w2b, nullptr, m2p, nullptr, nullptr, 0,
                                                       nullptr, nullptr, nullptr, nullptr, nullptr, nullptr,
                                                       4096, 768, 1536, 3072);
    k_red<<<3072, 256, 0, stream>>>(m2p, x2, mods, b2, (float*)d_out);
}

// Round 7
// 288.484 us; speedup vs baseline: 1.0144x; 1.0144x over previous
//
#include <hip/hip_runtime.h>
#include <hip/hip_bf16.h>

#define EPS 1e-5f

typedef __attribute__((ext_vector_type(8))) short bf16x8;
typedef __attribute__((ext_vector_type(4))) short bf16x4;
typedef __attribute__((ext_vector_type(4))) float f32x4;

__device__ __forceinline__ f32x4 mfma_bf16(bf16x8 a, bf16x8 b, f32x4 c) {
    return __builtin_amdgcn_mfma_f32_16x16x32_bf16(a, b, c, 0, 0, 0);
}

__device__ __forceinline__ void async_ld16(const void* g, void* l) {
    __builtin_amdgcn_global_load_lds(
        (const __attribute__((address_space(1))) void*)g,
        (__attribute__((address_space(3))) void*)l, 16, 0, 0);
}

// fast gelu: 0.5v(1+tanh z) == v * sigmoid(2z); one v_exp + one rcp.
__device__ __forceinline__ float fast_gelu(float v) {
    float z2 = 1.5957691216057308f * (v + 0.044715f * v * v * v);
    float e = __expf(z2);
    return v * e / (e + 1.f);
}

__device__ __forceinline__ float bf2f(short s) {
    union { float f; unsigned u; } v;
    v.u = ((unsigned)(unsigned short)s) << 16;
    return v.f;
}

__device__ __forceinline__ short f2bf_s(float x) {
    union { __hip_bfloat16 h; short s; } cv;
    cv.h = __float2bfloat16(x);
    return cv.s;
}

// ---------------- merged pre-work: f32->bf16 weight convert (blocks 0..27647)
// + adaLN modulation mods[b][i] = c[b].adaLN_w[i] + adaLN_b[i] (last 36 blocks)
__global__ void k_pre(const float* __restrict__ a, __hip_bfloat16* __restrict__ oa, int na,
                      const float* __restrict__ b, __hip_bfloat16* __restrict__ ob, int nb,
                      const float* __restrict__ c, __hip_bfloat16* __restrict__ oc, int nc,
                      const float* __restrict__ d, __hip_bfloat16* __restrict__ od, int nd,
                      const float* __restrict__ cond, const float* __restrict__ alw,
                      const float* __restrict__ alb, float* __restrict__ mods) {
    if (blockIdx.x >= 27648) {
        int i = (blockIdx.x - 27648) * 256 + threadIdx.x;   // 0..9215
        int bb = i / 4608, row = i - bb * 4608;
        const float4* cv = (const float4*)(cond + bb * 128);
        const float4* wv = (const float4*)(alw + (long)row * 128);
        float acc = 0.f;
#pragma unroll
        for (int k = 0; k < 32; ++k) {
            float4 x = cv[k], y = wv[k];
            acc += x.x * y.x + x.y * y.y + x.z * y.z + x.w * y.w;
        }
        mods[i] = acc + alb[row];
        return;
    }
    int i = blockIdx.x * 256 + threadIdx.x;
    if (i < na) { oa[i] = __float2bfloat16(a[i]); return; }
    i -= na;
    if (i < nb) { ob[i] = __float2bfloat16(b[i]); return; }
    i -= nb;
    if (i < nc) { oc[i] = __float2bfloat16(c[i]); return; }
    i -= nc;
    if (i < nd) od[i] = __float2bfloat16(d[i]);
}

// ---------------- fused LayerNorm + adaLN modulate, 1 wave per token
__global__ void k_ln_mod(const float* __restrict__ x, const float* __restrict__ w,
                         const float* __restrict__ mods, int shiftOff, int scaleOff,
                         __hip_bfloat16* __restrict__ out) {
    int token = blockIdx.x;      // 0..4095
    int lane = threadIdx.x;      // 0..63
    const float4* xr = (const float4*)(x + (long)token * 768);
    float4 v0 = xr[lane], v1 = xr[lane + 64], v2 = xr[lane + 128];
    float s  = v0.x + v0.y + v0.z + v0.w + v1.x + v1.y + v1.z + v1.w + v2.x + v2.y + v2.z + v2.w;
    float ss = v0.x*v0.x + v0.y*v0.y + v0.z*v0.z + v0.w*v0.w
             + v1.x*v1.x + v1.y*v1.y + v1.z*v1.z + v1.w*v1.w
             + v2.x*v2.x + v2.y*v2.y + v2.z*v2.z + v2.w*v2.w;
#pragma unroll
    for (int m = 32; m >= 1; m >>= 1) { s += __shfl_xor(s, m); ss += __shfl_xor(ss, m); }
    float mu = s * (1.f / 768.f);
    float var = ss * (1.f / 768.f) - mu * mu;
    float rs = rsqrtf(var + EPS);
    int b = token >> 11;
    const float* sh = mods + b * 4608 + shiftOff;
    const float* sc = mods + b * 4608 + scaleOff;
    __hip_bfloat16* o = out + (long)token * 768;
    float4 vv[3] = {v0, v1, v2};
#pragma unroll
    for (int kk = 0; kk < 3; ++kk) {
        int cbase = (lane + 64 * kk) * 4;
        const float* p = (const float*)&vv[kk];
#pragma unroll
        for (int j = 0; j < 4; ++j) {
            int col = cbase + j;
            float hv = (p[j] - mu) * rs * w[col] * (1.f + sc[col]) + sh[col];
            o[col] = __float2bfloat16(hv);
        }
    }
}

// ---------------- split-K reduce + mlp2 epilogue:
// out = x2 + gate*(p0 + p1 + bias), 4 cols per thread, all f32x4-vectorized.
__global__ void k_red(const __hip_bfloat16* __restrict__ p, const float* __restrict__ x2,
                      const float* __restrict__ mods, const float* __restrict__ bias,
                      float* __restrict__ out) {
    long base = ((long)blockIdx.x * 256 + threadIdx.x) * 4;    // 0..3145724
    int col = (int)(base % 768);
    int row = (int)(base / 768);
    int b = row >> 11;
    short4 a0 = *(const short4*)(p + base);
    short4 a1 = *(const short4*)(p + 3145728 + base);
    float4 xr = *(const float4*)(x2 + base);
    float4 gt = *(const float4*)(mods + b * 4608 + 3840 + col);
    float4 bs = *(const float4*)(bias + col);
    float4 o;
    o.x = xr.x + gt.x * (bf2f(a0.x) + bf2f(a1.x) + bs.x);
    o.y = xr.y + gt.y * (bf2f(a0.y) + bf2f(a1.y) + bs.y);
    o.z = xr.z + gt.z * (bf2f(a0.z) + bf2f(a1.z) + bs.z);
    o.w = xr.w + gt.w * (bf2f(a0.w) + bf2f(a1.w) + bs.w);
    *(float4*)(out + base) = o;
}

// ---------------- block-sparse flash attention, no-max softmax.
// R18: coalesced LDS staging of K/V (shared across 4 waves/workgroup) cut
// scattered-gather txns ~10x -> 56 -> ~36us. R19 deferred-PV pipeline:
// neutral (kept). Structure: workgroup = 4 q-blocks sharing a prefix,
// w=0..3 <-> (fl,blk) in {(0,b0),(1,b0),(0,b0+1),(1,b0+1)}; K/V chunks
// staged via coalesced global_load_lds (dbuf, vmcnt(4)), XOR-swizzled via
// pre-swizzled GLOBAL source (LDS dest linear, m104/m173); conflict-free
// ds_read_b128 fragments. Per-wave act masks; tail subtiles masked p=0.
__global__ __launch_bounds__(256) void k_attn(
    const __hip_bfloat16* __restrict__ q, const __hip_bfloat16* __restrict__ k,
    const __hip_bfloat16* __restrict__ vT, __hip_bfloat16* __restrict__ out) {
    __shared__ __hip_bfloat16 KL[2][64 * 64];   // [buf][key(64)][dim(64)] swizzled
    __shared__ __hip_bfloat16 VL[2][64 * 64];   // [buf][dim(64)][lkey(64)] swizzled
    __shared__ __hip_bfloat16 P[4][16 * 68];    // per-wave P tile
    int tid = threadIdx.x;
    int w = tid >> 6, lane = tid & 63, l15 = lane & 15, quad = lane >> 4;
    int idx = blockIdx.x;                  // 0..767
    int bh = idx % 24;                     // fastest: spreads across XCDs
    int gi = idx / 24;                     // 0..31
    int b0 = 62 - 2 * gi;                  // longest prefix first
    int fl = w & 1, blk = b0 + (w >> 1);
    int qblk = fl * 64 + blk;

    const __hip_bfloat16* Q = q + ((long)bh * 2048 + qblk * 16) * 64;
    bf16x8 qa = *(const bf16x8*)(Q + l15 * 64 + quad * 8);
    bf16x8 qb = *(const bf16x8*)(Q + l15 * 64 + 32 + quad * 8);
    const __hip_bfloat16* K = k + (long)bh * 2048 * 64;
    const __hip_bfloat16* V = vT + (long)bh * 64 * 2048;

    // staged subtile t -> global key base (clamped to 0 when out of range)
    auto kbase = [&](int t) -> int {
        if (t < b0 + 2) return 1024 + t * 16;
        if (t == b0 + 2) return b0 * 16;
        if (t == b0 + 3) return (b0 + 1) * 16;
        return 0;
    };
    // per-wave subtile activity (wave-uniform)
    auto active = [&](int t) -> bool {
        if (w == 0) return t < b0 || t == b0 + 2;
        if (w == 1) return t < b0 + 1;
        if (w == 2) return t < b0 + 1 || t == b0 + 3;
        return t < b0 + 2;
    };

    // staging decode constants (per thread: 2 K instrs + 2 V instrs)
    int kkr[2], kbs[2], vsi[2], vki[2];
#pragma unroll
    for (int i = 0; i < 2; ++i) {
        int o = i * 4096 + tid * 16;
        kkr[i] = o >> 7;
        int b = o & 127;
        kbs[i] = b ^ ((kkr[i] & 7) << 4);
        int lk2 = b ^ ((kkr[i] & 7) << 4);   // same row index for V decode
        vsi[i] = lk2 >> 5;
        vki[i] = (lk2 & 31) >> 1;
    }
    auto stage = [&](int ci, int buf) {
#pragma unroll
        for (int i = 0; i < 2; ++i) {
            int gk = kbase(4 * ci + (kkr[i] >> 4)) + (kkr[i] & 15);
            async_ld16(K + (long)gk * 64 + (kbs[i] >> 1),
                       (char*)&KL[buf][0] + i * 4096 + tid * 16);
        }
#pragma unroll
        for (int i = 0; i < 2; ++i) {
            int gk = kbase(4 * ci + vsi[i]) + vki[i];
            async_ld16(V + (long)kkr[i] * 2048 + gk,
                       (char*)&VL[buf][0] + i * 4096 + tid * 16);
        }
    };

    // fragment LDS offsets (shorts), swizzle matches staging
    int kfo[4][2], vfo[2][4];
#pragma unroll
    for (int s = 0; s < 4; ++s)
#pragma unroll
        for (int h = 0; h < 2; ++h)
            kfo[s][h] = (s * 16 + l15) * 64 +
                        (((h * 64 + quad * 16) ^ ((l15 & 7) << 4)) >> 1);
#pragma unroll
    for (int p2 = 0; p2 < 2; ++p2)
#pragma unroll
        for (int tt = 0; tt < 4; ++tt) {
            int d = tt * 16 + l15;
            int c = (p2 * 64 + (quad >> 1) * 32 + (quad & 1) * 16) ^ ((l15 & 7) << 4);
            vfo[p2][tt] = d * 64 + (c >> 1);
        }

    const f32x4 vzero = {0.f, 0.f, 0.f, 0.f};
    f32x4 o[4]; float l[4];
#pragma unroll
    for (int rr = 0; rr < 4; ++rr) { o[rr] = vzero; l[rr] = 0.f; }

    int nIter = (b0 + 7) >> 2;             // T = b0+4 staged subtiles
    __hip_bfloat16* Pw = &P[w][0];

    bf16x8 paP[2];          // prev-chunk P fragments (deferred PV)
    bf16x8 vfP[2][4];       // prev-chunk V fragments

    stage(0, 0);
    for (int ci = 0; ci < nIter; ++ci) {
        int cb = ci & 1;
        if (ci > 0) asm volatile("s_barrier" ::: "memory");      // buf cb^1 free
        if (ci + 1 < nIter) {
            stage(ci + 1, cb ^ 1);
            asm volatile("s_waitcnt vmcnt(4)" ::: "memory");     // chunk ci landed
        } else {
            asm volatile("s_waitcnt vmcnt(0)" ::: "memory");
        }
        asm volatile("s_barrier" ::: "memory");                  // chunk ci visible

        bf16x8 ka[4], kb8[4];
#pragma unroll
        for (int s = 0; s < 4; ++s) {
            ka[s]  = *(const bf16x8*)&KL[cb][kfo[s][0]];
            kb8[s] = *(const bf16x8*)&KL[cb][kfo[s][1]];
        }
        // scores: D[m=q][n=key]; lane: col=key=l15, row q=quad*4+rr
        f32x4 sc[4];
        __builtin_amdgcn_s_setprio(1);
#pragma unroll
        for (int s = 0; s < 4; ++s)
            sc[s] = mfma_bf16(qb, kb8[s], mfma_bf16(qa, ka[s], vzero));
        __builtin_amdgcn_s_setprio(0);
        bf16x8 vf[2][4];
#pragma unroll
        for (int p2 = 0; p2 < 2; ++p2)
#pragma unroll
            for (int tt = 0; tt < 4; ++tt)
                vf[p2][tt] = *(const bf16x8*)&VL[cb][vfo[p2][tt]];

        // exp + mask, accumulate l, write P[q][64 keys] (stride 68)
#pragma unroll
        for (int s = 0; s < 4; ++s) {
            bool a = active(4 * ci + s);
#pragma unroll
            for (int rr = 0; rr < 4; ++rr) {
                float pv = a ? __expf(sc[s][rr]) : 0.f;
                l[rr] += pv;
                Pw[(quad * 4 + rr) * 68 + s * 16 + l15] = __float2bfloat16(pv);
            }
        }
        // deferred PV of chunk ci-1: pure-register MFMAs execute while the
        // P(ci) writes drain -- hides the LDS round-trip latency.
        if (ci > 0) {
            __builtin_amdgcn_s_setprio(1);
#pragma unroll
            for (int p2 = 0; p2 < 2; ++p2)
#pragma unroll
                for (int tt = 0; tt < 4; ++tt)
                    o[tt] = mfma_bf16(paP[p2], vfP[p2][tt], o[tt]);
            __builtin_amdgcn_s_setprio(0);
        }
        asm volatile("s_waitcnt lgkmcnt(0)" ::: "memory");       // P(ci) visible
        bf16x8 pa[2];
#pragma unroll
        for (int p2 = 0; p2 < 2; ++p2) {
            union { bf16x4 h[2]; bf16x8 v; } u;
            u.h[0] = *(const bf16x4*)(Pw + l15 * 68 + p2 * 32 + quad * 8);
            u.h[1] = *(const bf16x4*)(Pw + l15 * 68 + p2 * 32 + quad * 8 + 4);
            pa[p2] = u.v;
        }
        // no drain: pa consumed next iteration (compiler emits counted wait)
#pragma unroll
        for (int p2 = 0; p2 < 2; ++p2) {
            paP[p2] = pa[p2];
#pragma unroll
            for (int tt = 0; tt < 4; ++tt) vfP[p2][tt] = vf[p2][tt];
        }
    }
    // final PV for the last chunk
    asm volatile("s_waitcnt lgkmcnt(0)" ::: "memory");
    __builtin_amdgcn_s_setprio(1);
#pragma unroll
    for (int p2 = 0; p2 < 2; ++p2)
#pragma unroll
        for (int tt = 0; tt < 4; ++tt)
            o[tt] = mfma_bf16(paP[p2], vfP[p2][tt], o[tt]);
    __builtin_amdgcn_s_setprio(0);

    // epilogue: per-wave, direct write (no merge needed)
    int b = bh / 12, h = bh - b * 12;
    int seqbase = qblk * 16;
#pragma unroll
    for (int rr = 0; rr < 4; ++rr) {
        float lr = l[rr];
#pragma unroll
        for (int msk = 1; msk < 16; msk <<= 1) lr += __shfl_xor(lr, msk, 16);
        float inv = 1.f / lr;
        long row = b * 2048 + seqbase + quad * 4 + rr;
#pragma unroll
        for (int tt = 0; tt < 4; ++tt)
            out[row * 768 + h * 64 + tt * 16 + l15] = __float2bfloat16(o[tt][rr] * inv);
    }
}

// ---------------- 128x64 bf16 GEMM, 2 LDS buffers, 2 waves/block.
// R20: counters showed the 128x128-tile GEMMs grid-starved (qkv: 576
// blocks = 2.25/CU vs 5-block LDS cap; MfmaUtil 12%, Occupancy 17.5%) --
// the depth-1 pipeline's vmcnt stall had ~1 other block to hide behind.
// TN=64 doubles the block count at the same wave count (24 KB LDS -> 6
// blocks/CU cap): qkv 1152, mlp1 1536, mlp2 768 blocks. Unified SMEM
// array so MODE4's vT epilogue can reuse staging LDS as a [64][132]
// transpose tile (scattered 2B/4KB-stride stores -> coalesced 256B rows).
// Depth-1 pipeline unchanged: stage(i+1) after top barrier, vmcnt(NINST),
// barrier, XOR-swizzled conflict-free ds_read_b128.
// MODE 1: Cf = mods[gate]*acc + resid   (attn proj + gate + residual)
// MODE 2: Cb = bf16(fast_gelu(acc + bias))   (mlp1)
// MODE 4: qkv + fused RoPE epilogue -> q (x0.125), k, vT bf16.
// MODE 5: split-K partial: Cb[z*M*N + row*N+col] = bf16(acc).
template <int MODE, int TN>
__global__ __launch_bounds__(128) void k_gemm(
    const __hip_bfloat16* __restrict__ A, const __hip_bfloat16* __restrict__ W,
    float* __restrict__ Cf, __hip_bfloat16* __restrict__ Cb,
    const float* __restrict__ bias, const float* __restrict__ mods, int gateOff,
    const float* __restrict__ resid, const float* __restrict__ cosb,
    const float* __restrict__ sinb, __hip_bfloat16* __restrict__ qo,
    __hip_bfloat16* __restrict__ ko, __hip_bfloat16* __restrict__ vo,
    int M, int N, int K, int lda) {
    static_assert(TN == 64, "all GEMMs run the 64-tile now");
    constexpr int NW = 2;
    constexpr int ACH = 512 / (NW * 64);          // 4
    constexpr int BCH = (TN * 4) / (NW * 64);     // 2
    constexpr int NINST = ACH + BCH;              // 6
    constexpr int SM_SHORTS = 2 * 128 * 32 + 2 * TN * 32;   // 12288 (24 KB)
    __shared__ __align__(16) __hip_bfloat16 SM[SM_SHORTS];
    int t = threadIdx.x;
    int wave = t >> 6, lane = t & 63, l15 = lane & 15, quad = lane >> 4;
    int wr = wave, wc = 0;
    int sw8 = (quad ^ ((l15 >> 1) & 3)) * 8;
    long bm = blockIdx.x, bn = blockIdx.y;
    const __hip_bfloat16* Ab = A + bm * 128 * lda + (long)blockIdx.z * K;
    const __hip_bfloat16* Wb = W + bn * TN * lda + (long)blockIdx.z * K;

    long soffA[ACH], soffB[BCH];
#pragma unroll
    for (int cc = 0; cc < ACH; ++cc) {
        int chunk = cc * NW * 64 + t;
        int row = chunk >> 2;
        int c = (chunk & 3) ^ ((row >> 1) & 3);
        soffA[cc] = (long)row * lda + c * 8;
    }
#pragma unroll
    for (int cc = 0; cc < BCH; ++cc) {
        int chunk = cc * NW * 64 + t;
        int row = chunk >> 2;
        int c = (chunk & 3) ^ ((row >> 1) & 3);
        soffB[cc] = (long)row * lda + c * 8;
    }
    auto stage = [&](int k0, int buf) {
        char* lAc = (char*)(SM + buf * 4096);
        char* lBc = (char*)(SM + 8192 + buf * (TN * 32));
#pragma unroll
        for (int cc = 0; cc < ACH; ++cc)
            async_ld16(Ab + soffA[cc] + k0, lAc + cc * (NW * 1024) + wave * 1024);
#pragma unroll
        for (int cc = 0; cc < BCH; ++cc)
            async_ld16(Wb + soffB[cc] + k0, lBc + cc * (NW * 1024) + wave * 1024);
    };

    f32x4 acc[4][4];
#pragma unroll
    for (int i = 0; i < 4; ++i)
#pragma unroll
        for (int j = 0; j < 4; ++j) acc[i][j] = (f32x4){0.f, 0.f, 0.f, 0.f};

    int nIter = K / 32;
    stage(0, 0);
    for (int i = 0; i < nIter; ++i) {
        int cb = i & 1;
        if (i > 0) asm volatile("s_barrier" ::: "memory");   // buf !cb free
        if (i + 1 < nIter) {
            stage((i + 1) * 32, cb ^ 1);
            asm volatile("s_waitcnt vmcnt(%0)" :: "n"(NINST) : "memory");  // tile i landed
        } else {
            asm volatile("s_waitcnt vmcnt(0)" ::: "memory");
        }
        asm volatile("s_barrier" ::: "memory");              // tile i visible
        bf16x8 af[4], bfr[4];
#pragma unroll
        for (int ii = 0; ii < 4; ++ii)
            af[ii] = *(const bf16x8*)&SM[cb * 4096 + (wr * 64 + ii * 16 + l15) * 32 + sw8];
#pragma unroll
        for (int j = 0; j < 4; ++j)
            bfr[j] = *(const bf16x8*)&SM[8192 + cb * (TN * 32) + (j * 16 + l15) * 32 + sw8];
#pragma unroll
        for (int ii = 0; ii < 4; ++ii)
#pragma unroll
            for (int j = 0; j < 4; ++j)
                acc[ii][j] = mfma_bf16(af[ii], bfr[j], acc[ii][j]);
    }

    if (MODE == 4) {
        int th = (int)bn / 12, h = (int)bn % 12;   // head-col = bn (TN=64)
        int sbase = ((int)bm * 128) & 2047;
        int b = ((int)bm * 128) >> 11;
        long bh_ = (long)b * 12 + h;
        if (th == 2) {
            // vT: RoPE into LDS [64 d][132 s] transpose tile (reuses staging
            // SMEM), then coalesced 256B dword rows. Replaces 2B/4KB-stride
            // scattered stores (64 txns/inst) with 1-txn coalesced stores.
            __syncthreads();
#pragma unroll
            for (int i = 0; i < 4; ++i) {
                int sl = wr * 64 + i * 16 + quad * 4;
#pragma unroll
                for (int j = 0; j < 2; ++j) {
                    int dh = j * 16 + l15;
                    bf16x4 p0, p1;
#pragma unroll
                    for (int r = 0; r < 4; ++r) {
                        int s = sbase + sl + r;
                        const float* cbp = cosb + s * 64;
                        const float* sbp = sinb + s * 64;
                        float a0f = acc[i][j][r], a1f = acc[i][j + 2][r];
                        p0[r] = f2bf_s(a0f * cbp[dh] - a1f * sbp[dh]);
                        p1[r] = f2bf_s(a1f * cbp[dh + 32] + a0f * sbp[dh + 32]);
                    }
                    *(bf16x4*)(SM + dh * 132 + sl) = p0;
                    *(bf16x4*)(SM + (dh + 32) * 132 + sl) = p1;
                }
            }
            __syncthreads();
            __hip_bfloat16* dst = vo + bh_ * 64 * 2048;
#pragma unroll
            for (int dd = 0; dd < 32; ++dd) {
                int d = wr * 32 + dd;
                unsigned pv = *(const unsigned*)(SM + d * 132 + lane * 2);
                *(unsigned*)(dst + (long)d * 2048 + sbase + lane * 2) = pv;
            }
            return;
        }
        // th 0/1: q (x0.125) / k, direct stores (16-lane 32B runs)
        float qs = (th == 0) ? 0.125f : 1.f;
        __hip_bfloat16* base = (th == 0) ? qo : ko;
#pragma unroll
        for (int i = 0; i < 4; ++i) {
#pragma unroll
            for (int r = 0; r < 4; ++r) {
                int s = sbase + wr * 64 + i * 16 + quad * 4 + r;
                const float* cbp = cosb + s * 64;
                const float* sbp = sinb + s * 64;
                __hip_bfloat16* d = base + (bh_ * 2048 + s) * 64;
#pragma unroll
                for (int j = 0; j < 2; ++j) {
                    int dh = j * 16 + l15;
                    float a0f = acc[i][j][r], a1f = acc[i][j + 2][r];
                    float o0 = a0f * cbp[dh] - a1f * sbp[dh];
                    float o1 = a1f * cbp[dh + 32] + a0f * sbp[dh + 32];
                    d[dh]      = __float2bfloat16(o0 * qs);
                    d[dh + 32] = __float2bfloat16(o1 * qs);
                }
            }
        }
        return;
    }

#pragma unroll
    for (int i = 0; i < 4; ++i) {
#pragma unroll
        for (int j = 0; j < 4; ++j) {
#pragma unroll
            for (int r = 0; r < 4; ++r) {
                int row = (int)bm * 128 + wr * 64 + i * 16 + quad * 4 + r;
                int col = (int)bn * TN + j * 16 + l15;
                float v = acc[i][j][r];
                long idx = (long)row * N + col;
                if (MODE == 1) {
                    Cf[idx] = mods[(row >> 11) * 4608 + gateOff + col] * v + resid[idx];
                } else if (MODE == 2) {
                    Cb[idx] = __float2bfloat16(fast_gelu(v + bias[col]));
                } else {   // MODE 5: split-K partial
                    Cb[(long)blockIdx.z * M * N + idx] = __float2bfloat16(v);
                }
            }
        }
    }
}

extern "C" void kernel_launch(void* const* d_in, const int* in_sizes, int n_in,
                              void* d_out, int out_size, void* d_ws, size_t ws_size,
                              hipStream_t stream) {
    const float* x    = (const float*)d_in[0];
    const float* c    = (const float*)d_in[1];
    const float* cosb = (const float*)d_in[2];
    const float* sinb = (const float*)d_in[3];
    // d_in[4] = mask: unused, computed analytically
    const float* n1w  = (const float*)d_in[5];
    const float* qkvw = (const float*)d_in[6];
    const float* aow  = (const float*)d_in[7];
    const float* n2w  = (const float*)d_in[8];
    const float* w1   = (const float*)d_in[9];
    const float* b1   = (const float*)d_in[10];
    const float* w2   = (const float*)d_in[11];
    const float* b2   = (const float*)d_in[12];
    const float* alw  = (const float*)d_in[13];
    const float* alb  = (const float*)d_in[14];

    char* ws = (char*)d_ws;
    size_t off = 0;
    auto alloc = [&](size_t bytes) -> void* {
        void* p = ws + off;
        off += (bytes + 255) & ~(size_t)255;
        return p;
    };
    float*          mods = (float*)alloc(2 * 4608 * 4);
    __hip_bfloat16* hbuf = (__hip_bfloat16*)alloc((size_t)4096 * 768 * 2);
    __hip_bfloat16* qb   = (__hip_bfloat16*)alloc((size_t)24 * 2048 * 64 * 2);
    __hip_bfloat16* kb   = (__hip_bfloat16*)alloc((size_t)24 * 2048 * 64 * 2);
    __hip_bfloat16* vT   = (__hip_bfloat16*)alloc((size_t)24 * 64 * 2048 * 2);
    __hip_bfloat16* abuf = (__hip_bfloat16*)alloc((size_t)4096 * 768 * 2);
    float*          x2   = (float*)alloc((size_t)4096 * 768 * 4);
    __hip_bfloat16* h2   = (__hip_bfloat16*)alloc((size_t)4096 * 768 * 2);
    __hip_bfloat16* m1   = (__hip_bfloat16*)alloc((size_t)4096 * 3072 * 2);
    __hip_bfloat16* m2p  = (__hip_bfloat16*)alloc((size_t)2 * 4096 * 768 * 2);
    __hip_bfloat16* wq   = (__hip_bfloat16*)alloc((size_t)2304 * 768 * 2);
    __hip_bfloat16* wa   = (__hip_bfloat16*)alloc((size_t)768 * 768 * 2);
    __hip_bfloat16* w1b  = (__hip_bfloat16*)alloc((size_t)3072 * 768 * 2);
    __hip_bfloat16* w2b  = (__hip_bfloat16*)alloc((size_t)768 * 3072 * 2);

    k_pre<<<27684, 256, 0, stream>>>(qkvw, wq, 2304 * 768, aow, wa, 768 * 768,
                                     w1, w1b, 3072 * 768, w2, w2b, 768 * 3072,
                                     c, alw, alb, mods);
    k_ln_mod<<<4096, 64, 0, stream>>>(x, n1w, mods, 0, 768, hbuf);
    // qkv GEMM + fused RoPE -> q, k, vT (64-tile: 1152 blocks, 4.5/CU)
    k_gemm<4, 64><<<dim3(32, 36), 128, 0, stream>>>(hbuf, wq, nullptr, nullptr, nullptr, nullptr, 0,
                                                    nullptr, cosb, sinb, qb, kb, vT,
                                                    4096, 2304, 768, 768);
    k_attn<<<768, 256, 0, stream>>>(qb, kb, vT, abuf);
    k_gemm<1, 64><<<dim3(32, 12), 128, 0, stream>>>(abuf, wa, x2, nullptr, nullptr, mods, 1536,
                                                    x, nullptr, nullptr, nullptr, nullptr, nullptr,
                                                    4096, 768, 768, 768);
    k_ln_mod<<<4096, 64, 0, stream>>>(x2, n2w, mods, 2304, 3072, h2);
    // mlp1 (64-tile: 1536 blocks, 6/CU)
    k_gemm<2, 64><<<dim3(32, 48), 128, 0, stream>>>(h2, w1b, nullptr, m1, b1, nullptr, 0,
                                                    nullptr, nullptr, nullptr, nullptr, nullptr, nullptr,
                                                    4096, 3072, 768, 768);
    // mlp2: split-K=2 (64-tile: 768 blocks)
    k_gemm<5, 64><<<dim3(32, 12, 2), 128, 0, stream>>>(m1, w2b, nullptr, m2p, nullptr, nullptr, 0,
                                                       nullptr, nullptr, nullptr, nullptr, nullptr, nullptr,
                                                       4096, 768, 1536, 3072);
    k_red<<<3072, 256, 0, stream>>>(m2p, x2, mods, b2, (float*)d_out);
}

// Round 8
// 280.561 us; speedup vs baseline: 1.0431x; 1.0282x over previous
//
#include <hip/hip_runtime.h>
#include <hip/hip_bf16.h>

#define EPS 1e-5f

typedef __attribute__((ext_vector_type(8))) short bf16x8;
typedef __attribute__((ext_vector_type(4))) short bf16x4;
typedef __attribute__((ext_vector_type(4))) float f32x4;

__device__ __forceinline__ f32x4 mfma_bf16(bf16x8 a, bf16x8 b, f32x4 c) {
    return __builtin_amdgcn_mfma_f32_16x16x32_bf16(a, b, c, 0, 0, 0);
}

__device__ __forceinline__ void async_ld16(const void* g, void* l) {
    __builtin_amdgcn_global_load_lds(
        (const __attribute__((address_space(1))) void*)g,
        (__attribute__((address_space(3))) void*)l, 16, 0, 0);
}

// fast gelu: 0.5v(1+tanh z) == v * sigmoid(2z); one v_exp + one rcp.
__device__ __forceinline__ float fast_gelu(float v) {
    float z2 = 1.5957691216057308f * (v + 0.044715f * v * v * v);
    float e = __expf(z2);
    return v * e / (e + 1.f);
}

__device__ __forceinline__ float bf2f(short s) {
    union { float f; unsigned u; } v;
    v.u = ((unsigned)(unsigned short)s) << 16;
    return v.f;
}

__device__ __forceinline__ short f2bf_s(float x) {
    union { __hip_bfloat16 h; short s; } cv;
    cv.h = __float2bfloat16(x);
    return cv.s;
}

// ---------------- merged pre-work: f32->bf16 weight convert (blocks 0..27647)
// + adaLN modulation mods[b][i] = c[b].adaLN_w[i] + adaLN_b[i] (last 36 blocks)
__global__ void k_pre(const float* __restrict__ a, __hip_bfloat16* __restrict__ oa, int na,
                      const float* __restrict__ b, __hip_bfloat16* __restrict__ ob, int nb,
                      const float* __restrict__ c, __hip_bfloat16* __restrict__ oc, int nc,
                      const float* __restrict__ d, __hip_bfloat16* __restrict__ od, int nd,
                      const float* __restrict__ cond, const float* __restrict__ alw,
                      const float* __restrict__ alb, float* __restrict__ mods) {
    if (blockIdx.x >= 27648) {
        int i = (blockIdx.x - 27648) * 256 + threadIdx.x;   // 0..9215
        int bb = i / 4608, row = i - bb * 4608;
        const float4* cv = (const float4*)(cond + bb * 128);
        const float4* wv = (const float4*)(alw + (long)row * 128);
        float acc = 0.f;
#pragma unroll
        for (int k = 0; k < 32; ++k) {
            float4 x = cv[k], y = wv[k];
            acc += x.x * y.x + x.y * y.y + x.z * y.z + x.w * y.w;
        }
        mods[i] = acc + alb[row];
        return;
    }
    int i = blockIdx.x * 256 + threadIdx.x;
    if (i < na) { oa[i] = __float2bfloat16(a[i]); return; }
    i -= na;
    if (i < nb) { ob[i] = __float2bfloat16(b[i]); return; }
    i -= nb;
    if (i < nc) { oc[i] = __float2bfloat16(c[i]); return; }
    i -= nc;
    if (i < nd) od[i] = __float2bfloat16(d[i]);
}

// ---------------- fused LayerNorm + adaLN modulate, 1 wave per token
__global__ void k_ln_mod(const float* __restrict__ x, const float* __restrict__ w,
                         const float* __restrict__ mods, int shiftOff, int scaleOff,
                         __hip_bfloat16* __restrict__ out) {
    int token = blockIdx.x;      // 0..4095
    int lane = threadIdx.x;      // 0..63
    const float4* xr = (const float4*)(x + (long)token * 768);
    float4 v0 = xr[lane], v1 = xr[lane + 64], v2 = xr[lane + 128];
    float s  = v0.x + v0.y + v0.z + v0.w + v1.x + v1.y + v1.z + v1.w + v2.x + v2.y + v2.z + v2.w;
    float ss = v0.x*v0.x + v0.y*v0.y + v0.z*v0.z + v0.w*v0.w
             + v1.x*v1.x + v1.y*v1.y + v1.z*v1.z + v1.w*v1.w
             + v2.x*v2.x + v2.y*v2.y + v2.z*v2.z + v2.w*v2.w;
#pragma unroll
    for (int m = 32; m >= 1; m >>= 1) { s += __shfl_xor(s, m); ss += __shfl_xor(ss, m); }
    float mu = s * (1.f / 768.f);
    float var = ss * (1.f / 768.f) - mu * mu;
    float rs = rsqrtf(var + EPS);
    int b = token >> 11;
    const float* sh = mods + b * 4608 + shiftOff;
    const float* sc = mods + b * 4608 + scaleOff;
    __hip_bfloat16* o = out + (long)token * 768;
    float4 vv[3] = {v0, v1, v2};
#pragma unroll
    for (int kk = 0; kk < 3; ++kk) {
        int cbase = (lane + 64 * kk) * 4;
        const float* p = (const float*)&vv[kk];
#pragma unroll
        for (int j = 0; j < 4; ++j) {
            int col = cbase + j;
            float hv = (p[j] - mu) * rs * w[col] * (1.f + sc[col]) + sh[col];
            o[col] = __float2bfloat16(hv);
        }
    }
}

// ---------------- split-K reduce + mlp2 epilogue:
// out = x2 + gate*(p0 + p1 + bias), 4 cols per thread, all f32x4-vectorized.
__global__ void k_red(const __hip_bfloat16* __restrict__ p, const float* __restrict__ x2,
                      const float* __restrict__ mods, const float* __restrict__ bias,
                      float* __restrict__ out) {
    long base = ((long)blockIdx.x * 256 + threadIdx.x) * 4;    // 0..3145724
    int col = (int)(base % 768);
    int row = (int)(base / 768);
    int b = row >> 11;
    short4 a0 = *(const short4*)(p + base);
    short4 a1 = *(const short4*)(p + 3145728 + base);
    float4 xr = *(const float4*)(x2 + base);
    float4 gt = *(const float4*)(mods + b * 4608 + 3840 + col);
    float4 bs = *(const float4*)(bias + col);
    float4 o;
    o.x = xr.x + gt.x * (bf2f(a0.x) + bf2f(a1.x) + bs.x);
    o.y = xr.y + gt.y * (bf2f(a0.y) + bf2f(a1.y) + bs.y);
    o.z = xr.z + gt.z * (bf2f(a0.z) + bf2f(a1.z) + bs.z);
    o.w = xr.w + gt.w * (bf2f(a0.w) + bf2f(a1.w) + bs.w);
    *(float4*)(out + base) = o;
}

// ---------------- block-sparse flash attention, no-max softmax.
// R18: coalesced LDS staging of K/V (shared across 4 waves/workgroup) cut
// scattered-gather txns ~10x -> 56 -> ~36us. R19 deferred-PV pipeline:
// neutral (kept). Structure: workgroup = 4 q-blocks sharing a prefix,
// w=0..3 <-> (fl,blk) in {(0,b0),(1,b0),(0,b0+1),(1,b0+1)}; K/V chunks
// staged via coalesced global_load_lds (dbuf, vmcnt(4)), XOR-swizzled via
// pre-swizzled GLOBAL source (LDS dest linear, m104/m173); conflict-free
// ds_read_b128 fragments. Per-wave act masks; tail subtiles masked p=0.
__global__ __launch_bounds__(256) void k_attn(
    const __hip_bfloat16* __restrict__ q, const __hip_bfloat16* __restrict__ k,
    const __hip_bfloat16* __restrict__ vT, __hip_bfloat16* __restrict__ out) {
    __shared__ __hip_bfloat16 KL[2][64 * 64];   // [buf][key(64)][dim(64)] swizzled
    __shared__ __hip_bfloat16 VL[2][64 * 64];   // [buf][dim(64)][lkey(64)] swizzled
    __shared__ __hip_bfloat16 P[4][16 * 68];    // per-wave P tile
    int tid = threadIdx.x;
    int w = tid >> 6, lane = tid & 63, l15 = lane & 15, quad = lane >> 4;
    int idx = blockIdx.x;                  // 0..767
    int bh = idx % 24;                     // fastest: spreads across XCDs
    int gi = idx / 24;                     // 0..31
    int b0 = 62 - 2 * gi;                  // longest prefix first
    int fl = w & 1, blk = b0 + (w >> 1);
    int qblk = fl * 64 + blk;

    const __hip_bfloat16* Q = q + ((long)bh * 2048 + qblk * 16) * 64;
    bf16x8 qa = *(const bf16x8*)(Q + l15 * 64 + quad * 8);
    bf16x8 qb = *(const bf16x8*)(Q + l15 * 64 + 32 + quad * 8);
    const __hip_bfloat16* K = k + (long)bh * 2048 * 64;
    const __hip_bfloat16* V = vT + (long)bh * 64 * 2048;

    // staged subtile t -> global key base (clamped to 0 when out of range)
    auto kbase = [&](int t) -> int {
        if (t < b0 + 2) return 1024 + t * 16;
        if (t == b0 + 2) return b0 * 16;
        if (t == b0 + 3) return (b0 + 1) * 16;
        return 0;
    };
    // per-wave subtile activity (wave-uniform)
    auto active = [&](int t) -> bool {
        if (w == 0) return t < b0 || t == b0 + 2;
        if (w == 1) return t < b0 + 1;
        if (w == 2) return t < b0 + 1 || t == b0 + 3;
        return t < b0 + 2;
    };

    // staging decode constants (per thread: 2 K instrs + 2 V instrs)
    int kkr[2], kbs[2], vsi[2], vki[2];
#pragma unroll
    for (int i = 0; i < 2; ++i) {
        int o = i * 4096 + tid * 16;
        kkr[i] = o >> 7;
        int b = o & 127;
        kbs[i] = b ^ ((kkr[i] & 7) << 4);
        int lk2 = b ^ ((kkr[i] & 7) << 4);   // same row index for V decode
        vsi[i] = lk2 >> 5;
        vki[i] = (lk2 & 31) >> 1;
    }
    auto stage = [&](int ci, int buf) {
#pragma unroll
        for (int i = 0; i < 2; ++i) {
            int gk = kbase(4 * ci + (kkr[i] >> 4)) + (kkr[i] & 15);
            async_ld16(K + (long)gk * 64 + (kbs[i] >> 1),
                       (char*)&KL[buf][0] + i * 4096 + tid * 16);
        }
#pragma unroll
        for (int i = 0; i < 2; ++i) {
            int gk = kbase(4 * ci + vsi[i]) + vki[i];
            async_ld16(V + (long)kkr[i] * 2048 + gk,
                       (char*)&VL[buf][0] + i * 4096 + tid * 16);
        }
    };

    // fragment LDS offsets (shorts), swizzle matches staging
    int kfo[4][2], vfo[2][4];
#pragma unroll
    for (int s = 0; s < 4; ++s)
#pragma unroll
        for (int h = 0; h < 2; ++h)
            kfo[s][h] = (s * 16 + l15) * 64 +
                        (((h * 64 + quad * 16) ^ ((l15 & 7) << 4)) >> 1);
#pragma unroll
    for (int p2 = 0; p2 < 2; ++p2)
#pragma unroll
        for (int tt = 0; tt < 4; ++tt) {
            int d = tt * 16 + l15;
            int c = (p2 * 64 + (quad >> 1) * 32 + (quad & 1) * 16) ^ ((l15 & 7) << 4);
            vfo[p2][tt] = d * 64 + (c >> 1);
        }

    const f32x4 vzero = {0.f, 0.f, 0.f, 0.f};
    f32x4 o[4]; float l[4];
#pragma unroll
    for (int rr = 0; rr < 4; ++rr) { o[rr] = vzero; l[rr] = 0.f; }

    int nIter = (b0 + 7) >> 2;             // T = b0+4 staged subtiles
    __hip_bfloat16* Pw = &P[w][0];

    bf16x8 paP[2];          // prev-chunk P fragments (deferred PV)
    bf16x8 vfP[2][4];       // prev-chunk V fragments

    stage(0, 0);
    for (int ci = 0; ci < nIter; ++ci) {
        int cb = ci & 1;
        if (ci > 0) asm volatile("s_barrier" ::: "memory");      // buf cb^1 free
        if (ci + 1 < nIter) {
            stage(ci + 1, cb ^ 1);
            asm volatile("s_waitcnt vmcnt(4)" ::: "memory");     // chunk ci landed
        } else {
            asm volatile("s_waitcnt vmcnt(0)" ::: "memory");
        }
        asm volatile("s_barrier" ::: "memory");                  // chunk ci visible

        bf16x8 ka[4], kb8[4];
#pragma unroll
        for (int s = 0; s < 4; ++s) {
            ka[s]  = *(const bf16x8*)&KL[cb][kfo[s][0]];
            kb8[s] = *(const bf16x8*)&KL[cb][kfo[s][1]];
        }
        // scores: D[m=q][n=key]; lane: col=key=l15, row q=quad*4+rr
        f32x4 sc[4];
        __builtin_amdgcn_s_setprio(1);
#pragma unroll
        for (int s = 0; s < 4; ++s)
            sc[s] = mfma_bf16(qb, kb8[s], mfma_bf16(qa, ka[s], vzero));
        __builtin_amdgcn_s_setprio(0);
        bf16x8 vf[2][4];
#pragma unroll
        for (int p2 = 0; p2 < 2; ++p2)
#pragma unroll
            for (int tt = 0; tt < 4; ++tt)
                vf[p2][tt] = *(const bf16x8*)&VL[cb][vfo[p2][tt]];

        // exp + mask, accumulate l, write P[q][64 keys] (stride 68)
#pragma unroll
        for (int s = 0; s < 4; ++s) {
            bool a = active(4 * ci + s);
#pragma unroll
            for (int rr = 0; rr < 4; ++rr) {
                float pv = a ? __expf(sc[s][rr]) : 0.f;
                l[rr] += pv;
                Pw[(quad * 4 + rr) * 68 + s * 16 + l15] = __float2bfloat16(pv);
            }
        }
        // deferred PV of chunk ci-1: pure-register MFMAs execute while the
        // P(ci) writes drain -- hides the LDS round-trip latency.
        if (ci > 0) {
            __builtin_amdgcn_s_setprio(1);
#pragma unroll
            for (int p2 = 0; p2 < 2; ++p2)
#pragma unroll
                for (int tt = 0; tt < 4; ++tt)
                    o[tt] = mfma_bf16(paP[p2], vfP[p2][tt], o[tt]);
            __builtin_amdgcn_s_setprio(0);
        }
        asm volatile("s_waitcnt lgkmcnt(0)" ::: "memory");       // P(ci) visible
        bf16x8 pa[2];
#pragma unroll
        for (int p2 = 0; p2 < 2; ++p2) {
            union { bf16x4 h[2]; bf16x8 v; } u;
            u.h[0] = *(const bf16x4*)(Pw + l15 * 68 + p2 * 32 + quad * 8);
            u.h[1] = *(const bf16x4*)(Pw + l15 * 68 + p2 * 32 + quad * 8 + 4);
            pa[p2] = u.v;
        }
        // no drain: pa consumed next iteration (compiler emits counted wait)
#pragma unroll
        for (int p2 = 0; p2 < 2; ++p2) {
            paP[p2] = pa[p2];
#pragma unroll
            for (int tt = 0; tt < 4; ++tt) vfP[p2][tt] = vf[p2][tt];
        }
    }
    // final PV for the last chunk
    asm volatile("s_waitcnt lgkmcnt(0)" ::: "memory");
    __builtin_amdgcn_s_setprio(1);
#pragma unroll
    for (int p2 = 0; p2 < 2; ++p2)
#pragma unroll
        for (int tt = 0; tt < 4; ++tt)
            o[tt] = mfma_bf16(paP[p2], vfP[p2][tt], o[tt]);
    __builtin_amdgcn_s_setprio(0);

    // epilogue: per-wave, direct write (no merge needed)
    int b = bh / 12, h = bh - b * 12;
    int seqbase = qblk * 16;
#pragma unroll
    for (int rr = 0; rr < 4; ++rr) {
        float lr = l[rr];
#pragma unroll
        for (int msk = 1; msk < 16; msk <<= 1) lr += __shfl_xor(lr, msk, 16);
        float inv = 1.f / lr;
        long row = b * 2048 + seqbase + quad * 4 + rr;
#pragma unroll
        for (int tt = 0; tt < 4; ++tt)
            out[row * 768 + h * 64 + tt * 16 + l15] = __float2bfloat16(o[tt][rr] * inv);
    }
}

// ---------------- 128xTN bf16 GEMM, 2 LDS buffers.
// R21: traffic model -- staging bytes = MNK*2*(1/128 + 1/TN) flow through
// L2/L3; at TN=64 mlp1 pulled 453MB in 43.5us = 10.4 TB/s ~= the Infinity
// Cache BW ceiling (FETCH shows only 21.7MB from HBM). That, not latency,
// is why MfmaUtil stuck at 17% and every scheduling tweak was neutral.
// Fixes: (a) XCD-aware bijective block swizzle -- lin = bx + 32*by;
// xcd = lin&7; bm = 4*xcd + (slot&3); bn = slot>>2. Each XCD owns 4
// contiguous bm for ALL bn: its 4 A-tiles stay L2-resident and each
// B-tile is fetched into its L2 once, consumed by 4 co-resident blocks
// (per-XCD beyond-L2 traffic: mlp1 302MB -> ~50MB). Bijective since
// gridDim.x==32 always (ERRATA #11 respected). (b) mlp1 back to TN=128
// (R7's TN=64 raised its traffic 1.5x; 768 blocks = 3/CU all-resident).
// Depth-1 pipeline unchanged: stage(i+1) after top barrier, vmcnt(NINST),
// barrier, XOR-swizzled conflict-free ds_read_b128.
// MODE 1: Cf = mods[gate]*acc + resid   (attn proj + gate + residual)
// MODE 2: Cb = bf16(fast_gelu(acc + bias))   (mlp1)
// MODE 4: qkv + fused RoPE epilogue -> q (x0.125), k, vT bf16 (TN=64 only).
// MODE 5: split-K partial: Cb[z*M*N + row*N+col] = bf16(acc).
template <int MODE, int TN>
__global__ __launch_bounds__(TN == 128 ? 256 : 128) void k_gemm(
    const __hip_bfloat16* __restrict__ A, const __hip_bfloat16* __restrict__ W,
    float* __restrict__ Cf, __hip_bfloat16* __restrict__ Cb,
    const float* __restrict__ bias, const float* __restrict__ mods, int gateOff,
    const float* __restrict__ resid, const float* __restrict__ cosb,
    const float* __restrict__ sinb, __hip_bfloat16* __restrict__ qo,
    __hip_bfloat16* __restrict__ ko, __hip_bfloat16* __restrict__ vo,
    int M, int N, int K, int lda) {
    constexpr int NW = (TN == 128) ? 4 : 2;
    constexpr int ACH = 512 / (NW * 64);
    constexpr int BCH = (TN * 4) / (NW * 64);
    constexpr int NINST = ACH + BCH;
    constexpr int SM_SHORTS = 2 * 128 * 32 + 2 * TN * 32;
    __shared__ __align__(16) __hip_bfloat16 SM[SM_SHORTS];
    int t = threadIdx.x;
    int wave = t >> 6, lane = t & 63, l15 = lane & 15, quad = lane >> 4;
    int wr = (TN == 128) ? (wave >> 1) : wave;
    int wc = (TN == 128) ? (wave & 1) : 0;
    int sw8 = (quad ^ ((l15 >> 1) & 3)) * 8;
    // XCD-aware swizzle: each XCD owns bm in [4*xcd, 4*xcd+4) for all bn.
    int lin = (int)blockIdx.x + 32 * (int)blockIdx.y;
    int slot = lin >> 3;
    long bm = 4 * (lin & 7) + (slot & 3);
    long bn = slot >> 2;
    const __hip_bfloat16* Ab = A + bm * 128 * lda + (long)blockIdx.z * K;
    const __hip_bfloat16* Wb = W + bn * TN * lda + (long)blockIdx.z * K;

    long soffA[ACH], soffB[BCH];
#pragma unroll
    for (int cc = 0; cc < ACH; ++cc) {
        int chunk = cc * NW * 64 + t;
        int row = chunk >> 2;
        int c = (chunk & 3) ^ ((row >> 1) & 3);
        soffA[cc] = (long)row * lda + c * 8;
    }
#pragma unroll
    for (int cc = 0; cc < BCH; ++cc) {
        int chunk = cc * NW * 64 + t;
        int row = chunk >> 2;
        int c = (chunk & 3) ^ ((row >> 1) & 3);
        soffB[cc] = (long)row * lda + c * 8;
    }
    auto stage = [&](int k0, int buf) {
        char* lAc = (char*)(SM + buf * 4096);
        char* lBc = (char*)(SM + 8192 + buf * (TN * 32));
#pragma unroll
        for (int cc = 0; cc < ACH; ++cc)
            async_ld16(Ab + soffA[cc] + k0, lAc + cc * (NW * 1024) + wave * 1024);
#pragma unroll
        for (int cc = 0; cc < BCH; ++cc)
            async_ld16(Wb + soffB[cc] + k0, lBc + cc * (NW * 1024) + wave * 1024);
    };

    f32x4 acc[4][4];
#pragma unroll
    for (int i = 0; i < 4; ++i)
#pragma unroll
        for (int j = 0; j < 4; ++j) acc[i][j] = (f32x4){0.f, 0.f, 0.f, 0.f};

    int nIter = K / 32;
    stage(0, 0);
    for (int i = 0; i < nIter; ++i) {
        int cb = i & 1;
        if (i > 0) asm volatile("s_barrier" ::: "memory");   // buf !cb free
        if (i + 1 < nIter) {
            stage((i + 1) * 32, cb ^ 1);
            asm volatile("s_waitcnt vmcnt(%0)" :: "n"(NINST) : "memory");  // tile i landed
        } else {
            asm volatile("s_waitcnt vmcnt(0)" ::: "memory");
        }
        asm volatile("s_barrier" ::: "memory");              // tile i visible
        bf16x8 af[4], bfr[4];
#pragma unroll
        for (int ii = 0; ii < 4; ++ii)
            af[ii] = *(const bf16x8*)&SM[cb * 4096 + (wr * 64 + ii * 16 + l15) * 32 + sw8];
#pragma unroll
        for (int j = 0; j < 4; ++j)
            bfr[j] = *(const bf16x8*)&SM[8192 + cb * (TN * 32) + (wc * 64 + j * 16 + l15) * 32 + sw8];
#pragma unroll
        for (int ii = 0; ii < 4; ++ii)
#pragma unroll
            for (int j = 0; j < 4; ++j)
                acc[ii][j] = mfma_bf16(af[ii], bfr[j], acc[ii][j]);
    }

    if (MODE == 4) {
        static_assert(MODE != 4 || TN == 64, "MODE4 requires TN=64");
        int th = (int)bn / 12, h = (int)bn % 12;   // head-col = bn (TN=64)
        int sbase = ((int)bm * 128) & 2047;
        int b = ((int)bm * 128) >> 11;
        long bh_ = (long)b * 12 + h;
        if (th == 2) {
            // vT: RoPE into LDS [64 d][132 s] transpose tile (reuses staging
            // SMEM), then coalesced 256B dword rows. Replaces 2B/4KB-stride
            // scattered stores (64 txns/inst) with 1-txn coalesced stores.
            __syncthreads();
#pragma unroll
            for (int i = 0; i < 4; ++i) {
                int sl = wr * 64 + i * 16 + quad * 4;
#pragma unroll
                for (int j = 0; j < 2; ++j) {
                    int dh = j * 16 + l15;
                    bf16x4 p0, p1;
#pragma unroll
                    for (int r = 0; r < 4; ++r) {
                        int s = sbase + sl + r;
                        const float* cbp = cosb + s * 64;
                        const float* sbp = sinb + s * 64;
                        float a0f = acc[i][j][r], a1f = acc[i][j + 2][r];
                        p0[r] = f2bf_s(a0f * cbp[dh] - a1f * sbp[dh]);
                        p1[r] = f2bf_s(a1f * cbp[dh + 32] + a0f * sbp[dh + 32]);
                    }
                    *(bf16x4*)(SM + dh * 132 + sl) = p0;
                    *(bf16x4*)(SM + (dh + 32) * 132 + sl) = p1;
                }
            }
            __syncthreads();
            __hip_bfloat16* dst = vo + bh_ * 64 * 2048;
#pragma unroll
            for (int dd = 0; dd < 32; ++dd) {
                int d = wr * 32 + dd;
                unsigned pv = *(const unsigned*)(SM + d * 132 + lane * 2);
                *(unsigned*)(dst + (long)d * 2048 + sbase + lane * 2) = pv;
            }
            return;
        }
        // th 0/1: q (x0.125) / k, direct stores (16-lane 32B runs)
        float qs = (th == 0) ? 0.125f : 1.f;
        __hip_bfloat16* base = (th == 0) ? qo : ko;
#pragma unroll
        for (int i = 0; i < 4; ++i) {
#pragma unroll
            for (int r = 0; r < 4; ++r) {
                int s = sbase + wr * 64 + i * 16 + quad * 4 + r;
                const float* cbp = cosb + s * 64;
                const float* sbp = sinb + s * 64;
                __hip_bfloat16* d = base + (bh_ * 2048 + s) * 64;
#pragma unroll
                for (int j = 0; j < 2; ++j) {
                    int dh = j * 16 + l15;
                    float a0f = acc[i][j][r], a1f = acc[i][j + 2][r];
                    float o0 = a0f * cbp[dh] - a1f * sbp[dh];
                    float o1 = a1f * cbp[dh + 32] + a0f * sbp[dh + 32];
                    d[dh]      = __float2bfloat16(o0 * qs);
                    d[dh + 32] = __float2bfloat16(o1 * qs);
                }
            }
        }
        return;
    }

#pragma unroll
    for (int i = 0; i < 4; ++i) {
#pragma unroll
        for (int j = 0; j < 4; ++j) {
#pragma unroll
            for (int r = 0; r < 4; ++r) {
                int row = (int)bm * 128 + wr * 64 + i * 16 + quad * 4 + r;
                int col = (int)bn * TN + wc * 64 + j * 16 + l15;
                float v = acc[i][j][r];
                long idx = (long)row * N + col;
                if (MODE == 1) {
                    Cf[idx] = mods[(row >> 11) * 4608 + gateOff + col] * v + resid[idx];
                } else if (MODE == 2) {
                    Cb[idx] = __float2bfloat16(fast_gelu(v + bias[col]));
                } else {   // MODE 5: split-K partial
                    Cb[(long)blockIdx.z * M * N + idx] = __float2bfloat16(v);
                }
            }
        }
    }
}

extern "C" void kernel_launch(void* const* d_in, const int* in_sizes, int n_in,
                              void* d_out, int out_size, void* d_ws, size_t ws_size,
                              hipStream_t stream) {
    const float* x    = (const float*)d_in[0];
    const float* c    = (const float*)d_in[1];
    const float* cosb = (const float*)d_in[2];
    const float* sinb = (const float*)d_in[3];
    // d_in[4] = mask: unused, computed analytically
    const float* n1w  = (const float*)d_in[5];
    const float* qkvw = (const float*)d_in[6];
    const float* aow  = (const float*)d_in[7];
    const float* n2w  = (const float*)d_in[8];
    const float* w1   = (const float*)d_in[9];
    const float* b1   = (const float*)d_in[10];
    const float* w2   = (const float*)d_in[11];
    const float* b2   = (const float*)d_in[12];
    const float* alw  = (const float*)d_in[13];
    const float* alb  = (const float*)d_in[14];

    char* ws = (char*)d_ws;
    size_t off = 0;
    auto alloc = [&](size_t bytes) -> void* {
        void* p = ws + off;
        off += (bytes + 255) & ~(size_t)255;
        return p;
    };
    float*          mods = (float*)alloc(2 * 4608 * 4);
    __hip_bfloat16* hbuf = (__hip_bfloat16*)alloc((size_t)4096 * 768 * 2);
    __hip_bfloat16* qb   = (__hip_bfloat16*)alloc((size_t)24 * 2048 * 64 * 2);
    __hip_bfloat16* kb   = (__hip_bfloat16*)alloc((size_t)24 * 2048 * 64 * 2);
    __hip_bfloat16* vT   = (__hip_bfloat16*)alloc((size_t)24 * 64 * 2048 * 2);
    __hip_bfloat16* abuf = (__hip_bfloat16*)alloc((size_t)4096 * 768 * 2);
    float*          x2   = (float*)alloc((size_t)4096 * 768 * 4);
    __hip_bfloat16* h2   = (__hip_bfloat16*)alloc((size_t)4096 * 768 * 2);
    __hip_bfloat16* m1   = (__hip_bfloat16*)alloc((size_t)4096 * 3072 * 2);
    __hip_bfloat16* m2p  = (__hip_bfloat16*)alloc((size_t)2 * 4096 * 768 * 2);
    __hip_bfloat16* wq   = (__hip_bfloat16*)alloc((size_t)2304 * 768 * 2);
    __hip_bfloat16* wa   = (__hip_bfloat16*)alloc((size_t)768 * 768 * 2);
    __hip_bfloat16* w1b  = (__hip_bfloat16*)alloc((size_t)3072 * 768 * 2);
    __hip_bfloat16* w2b  = (__hip_bfloat16*)alloc((size_t)768 * 3072 * 2);

    k_pre<<<27684, 256, 0, stream>>>(qkvw, wq, 2304 * 768, aow, wa, 768 * 768,
                                     w1, w1b, 3072 * 768, w2, w2b, 768 * 3072,
                                     c, alw, alb, mods);
    k_ln_mod<<<4096, 64, 0, stream>>>(x, n1w, mods, 0, 768, hbuf);
    // qkv GEMM + fused RoPE -> q, k, vT (64-tile: 1152 blocks, XCD-swizzled)
    k_gemm<4, 64><<<dim3(32, 36), 128, 0, stream>>>(hbuf, wq, nullptr, nullptr, nullptr, nullptr, 0,
                                                    nullptr, cosb, sinb, qb, kb, vT,
                                                    4096, 2304, 768, 768);
    k_attn<<<768, 256, 0, stream>>>(qb, kb, vT, abuf);
    k_gemm<1, 64><<<dim3(32, 12), 128, 0, stream>>>(abuf, wa, x2, nullptr, nullptr, mods, 1536,
                                                    x, nullptr, nullptr, nullptr, nullptr, nullptr,
                                                    4096, 768, 768, 768);
    k_ln_mod<<<4096, 64, 0, stream>>>(x2, n2w, mods, 2304, 3072, h2);
    // mlp1: back to 128x128 (768 blocks = 3/CU, lowest-traffic tiling)
    k_gemm<2, 128><<<dim3(32, 24), 256, 0, stream>>>(h2, w1b, nullptr, m1, b1, nullptr, 0,
                                                     nullptr, nullptr, nullptr, nullptr, nullptr, nullptr,
                                                     4096, 3072, 768, 768);
    // mlp2: split-K=2 (64-tile: 768 blocks)
    k_gemm<5, 64><<<dim3(32, 12, 2), 128, 0, stream>>>(m1, w2b, nullptr, m2p, nullptr, nullptr, 0,
                                                       nullptr, nullptr, nullptr, nullptr, nullptr, nullptr,
                                                       4096, 768, 1536, 3072);
    k_red<<<3072, 256, 0, stream>>>(m2p, x2, mods, b2, (float*)d_out);
}

// Round 9
// 278.897 us; speedup vs baseline: 1.0493x; 1.0060x over previous
//
#include <hip/hip_runtime.h>
#include <hip/hip_bf16.h>

#define EPS 1e-5f

typedef __attribute__((ext_vector_type(8))) short bf16x8;
typedef __attribute__((ext_vector_type(4))) short bf16x4;
typedef __attribute__((ext_vector_type(4))) float f32x4;

__device__ __forceinline__ f32x4 mfma_bf16(bf16x8 a, bf16x8 b, f32x4 c) {
    return __builtin_amdgcn_mfma_f32_16x16x32_bf16(a, b, c, 0, 0, 0);
}

__device__ __forceinline__ void async_ld16(const void* g, void* l) {
    __builtin_amdgcn_global_load_lds(
        (const __attribute__((address_space(1))) void*)g,
        (__attribute__((address_space(3))) void*)l, 16, 0, 0);
}

// fast gelu: 0.5v(1+tanh z) == v * sigmoid(2z); one v_exp + one rcp.
__device__ __forceinline__ float fast_gelu(float v) {
    float z2 = 1.5957691216057308f * (v + 0.044715f * v * v * v);
    float e = __expf(z2);
    return v * e / (e + 1.f);
}

__device__ __forceinline__ float bf2f(short s) {
    union { float f; unsigned u; } v;
    v.u = ((unsigned)(unsigned short)s) << 16;
    return v.f;
}

__device__ __forceinline__ short f2bf_s(float x) {
    union { __hip_bfloat16 h; short s; } cv;
    cv.h = __float2bfloat16(x);
    return cv.s;
}

// ---------------- merged pre-work: f32->bf16 weight convert (blocks 0..27647)
// + adaLN modulation mods[b][i] = c[b].adaLN_w[i] + adaLN_b[i] (last 36 blocks)
__global__ void k_pre(const float* __restrict__ a, __hip_bfloat16* __restrict__ oa, int na,
                      const float* __restrict__ b, __hip_bfloat16* __restrict__ ob, int nb,
                      const float* __restrict__ c, __hip_bfloat16* __restrict__ oc, int nc,
                      const float* __restrict__ d, __hip_bfloat16* __restrict__ od, int nd,
                      const float* __restrict__ cond, const float* __restrict__ alw,
                      const float* __restrict__ alb, float* __restrict__ mods) {
    if (blockIdx.x >= 27648) {
        int i = (blockIdx.x - 27648) * 256 + threadIdx.x;   // 0..9215
        int bb = i / 4608, row = i - bb * 4608;
        const float4* cv = (const float4*)(cond + bb * 128);
        const float4* wv = (const float4*)(alw + (long)row * 128);
        float acc = 0.f;
#pragma unroll
        for (int k = 0; k < 32; ++k) {
            float4 x = cv[k], y = wv[k];
            acc += x.x * y.x + x.y * y.y + x.z * y.z + x.w * y.w;
        }
        mods[i] = acc + alb[row];
        return;
    }
    int i = blockIdx.x * 256 + threadIdx.x;
    if (i < na) { oa[i] = __float2bfloat16(a[i]); return; }
    i -= na;
    if (i < nb) { ob[i] = __float2bfloat16(b[i]); return; }
    i -= nb;
    if (i < nc) { oc[i] = __float2bfloat16(c[i]); return; }
    i -= nc;
    if (i < nd) od[i] = __float2bfloat16(d[i]);
}

// ---------------- fused LayerNorm + adaLN modulate, 1 wave per token
__global__ void k_ln_mod(const float* __restrict__ x, const float* __restrict__ w,
                         const float* __restrict__ mods, int shiftOff, int scaleOff,
                         __hip_bfloat16* __restrict__ out) {
    int token = blockIdx.x;      // 0..4095
    int lane = threadIdx.x;      // 0..63
    const float4* xr = (const float4*)(x + (long)token * 768);
    float4 v0 = xr[lane], v1 = xr[lane + 64], v2 = xr[lane + 128];
    float s  = v0.x + v0.y + v0.z + v0.w + v1.x + v1.y + v1.z + v1.w + v2.x + v2.y + v2.z + v2.w;
    float ss = v0.x*v0.x + v0.y*v0.y + v0.z*v0.z + v0.w*v0.w
             + v1.x*v1.x + v1.y*v1.y + v1.z*v1.z + v1.w*v1.w
             + v2.x*v2.x + v2.y*v2.y + v2.z*v2.z + v2.w*v2.w;
#pragma unroll
    for (int m = 32; m >= 1; m >>= 1) { s += __shfl_xor(s, m); ss += __shfl_xor(ss, m); }
    float mu = s * (1.f / 768.f);
    float var = ss * (1.f / 768.f) - mu * mu;
    float rs = rsqrtf(var + EPS);
    int b = token >> 11;
    const float* sh = mods + b * 4608 + shiftOff;
    const float* sc = mods + b * 4608 + scaleOff;
    __hip_bfloat16* o = out + (long)token * 768;
    float4 vv[3] = {v0, v1, v2};
#pragma unroll
    for (int kk = 0; kk < 3; ++kk) {
        int cbase = (lane + 64 * kk) * 4;
        const float* p = (const float*)&vv[kk];
#pragma unroll
        for (int j = 0; j < 4; ++j) {
            int col = cbase + j;
            float hv = (p[j] - mu) * rs * w[col] * (1.f + sc[col]) + sh[col];
            o[col] = __float2bfloat16(hv);
        }
    }
}

// ---------------- split-K reduce + mlp2 epilogue (4 partials):
// out = x2 + gate*(p0+p1+p2+p3 + bias), 4 cols per thread, f32x4-vectorized.
__global__ void k_red(const __hip_bfloat16* __restrict__ p, const float* __restrict__ x2,
                      const float* __restrict__ mods, const float* __restrict__ bias,
                      float* __restrict__ out) {
    long base = ((long)blockIdx.x * 256 + threadIdx.x) * 4;    // 0..3145724
    int col = (int)(base % 768);
    int row = (int)(base / 768);
    int b = row >> 11;
    float sx = 0.f, sy = 0.f, sz = 0.f, sw = 0.f;
#pragma unroll
    for (int z = 0; z < 4; ++z) {
        short4 a = *(const short4*)(p + (long)z * 3145728 + base);
        sx += bf2f(a.x); sy += bf2f(a.y); sz += bf2f(a.z); sw += bf2f(a.w);
    }
    float4 xr = *(const float4*)(x2 + base);
    float4 gt = *(const float4*)(mods + b * 4608 + 3840 + col);
    float4 bs = *(const float4*)(bias + col);
    float4 o;
    o.x = xr.x + gt.x * (sx + bs.x);
    o.y = xr.y + gt.y * (sy + bs.y);
    o.z = xr.z + gt.z * (sz + bs.z);
    o.w = xr.w + gt.w * (sw + bs.w);
    *(float4*)(out + base) = o;
}

// ---------------- block-sparse flash attention, no-max softmax.
// R18: coalesced LDS staging of K/V (shared across 4 waves/workgroup) cut
// scattered-gather txns ~10x -> 56 -> ~36us. R19 deferred-PV pipeline:
// neutral (kept). Structure: workgroup = 4 q-blocks sharing a prefix,
// w=0..3 <-> (fl,blk) in {(0,b0),(1,b0),(0,b0+1),(1,b0+1)}; K/V chunks
// staged via coalesced global_load_lds (dbuf, vmcnt(4)), XOR-swizzled via
// pre-swizzled GLOBAL source (LDS dest linear, m104/m173); conflict-free
// ds_read_b128 fragments. Per-wave act masks; tail subtiles masked p=0.
__global__ __launch_bounds__(256) void k_attn(
    const __hip_bfloat16* __restrict__ q, const __hip_bfloat16* __restrict__ k,
    const __hip_bfloat16* __restrict__ vT, __hip_bfloat16* __restrict__ out) {
    __shared__ __hip_bfloat16 KL[2][64 * 64];   // [buf][key(64)][dim(64)] swizzled
    __shared__ __hip_bfloat16 VL[2][64 * 64];   // [buf][dim(64)][lkey(64)] swizzled
    __shared__ __hip_bfloat16 P[4][16 * 68];    // per-wave P tile
    int tid = threadIdx.x;
    int w = tid >> 6, lane = tid & 63, l15 = lane & 15, quad = lane >> 4;
    int idx = blockIdx.x;                  // 0..767
    int bh = idx % 24;                     // fastest: spreads across XCDs
    int gi = idx / 24;                     // 0..31
    int b0 = 62 - 2 * gi;                  // longest prefix first
    int fl = w & 1, blk = b0 + (w >> 1);
    int qblk = fl * 64 + blk;

    const __hip_bfloat16* Q = q + ((long)bh * 2048 + qblk * 16) * 64;
    bf16x8 qa = *(const bf16x8*)(Q + l15 * 64 + quad * 8);
    bf16x8 qb = *(const bf16x8*)(Q + l15 * 64 + 32 + quad * 8);
    const __hip_bfloat16* K = k + (long)bh * 2048 * 64;
    const __hip_bfloat16* V = vT + (long)bh * 64 * 2048;

    // staged subtile t -> global key base (clamped to 0 when out of range)
    auto kbase = [&](int t) -> int {
        if (t < b0 + 2) return 1024 + t * 16;
        if (t == b0 + 2) return b0 * 16;
        if (t == b0 + 3) return (b0 + 1) * 16;
        return 0;
    };
    // per-wave subtile activity (wave-uniform)
    auto active = [&](int t) -> bool {
        if (w == 0) return t < b0 || t == b0 + 2;
        if (w == 1) return t < b0 + 1;
        if (w == 2) return t < b0 + 1 || t == b0 + 3;
        return t < b0 + 2;
    };

    // staging decode constants (per thread: 2 K instrs + 2 V instrs)
    int kkr[2], kbs[2], vsi[2], vki[2];
#pragma unroll
    for (int i = 0; i < 2; ++i) {
        int o = i * 4096 + tid * 16;
        kkr[i] = o >> 7;
        int b = o & 127;
        kbs[i] = b ^ ((kkr[i] & 7) << 4);
        int lk2 = b ^ ((kkr[i] & 7) << 4);   // same row index for V decode
        vsi[i] = lk2 >> 5;
        vki[i] = (lk2 & 31) >> 1;
    }
    auto stage = [&](int ci, int buf) {
#pragma unroll
        for (int i = 0; i < 2; ++i) {
            int gk = kbase(4 * ci + (kkr[i] >> 4)) + (kkr[i] & 15);
            async_ld16(K + (long)gk * 64 + (kbs[i] >> 1),
                       (char*)&KL[buf][0] + i * 4096 + tid * 16);
        }
#pragma unroll
        for (int i = 0; i < 2; ++i) {
            int gk = kbase(4 * ci + vsi[i]) + vki[i];
            async_ld16(V + (long)kkr[i] * 2048 + gk,
                       (char*)&VL[buf][0] + i * 4096 + tid * 16);
        }
    };

    // fragment LDS offsets (shorts), swizzle matches staging
    int kfo[4][2], vfo[2][4];
#pragma unroll
    for (int s = 0; s < 4; ++s)
#pragma unroll
        for (int h = 0; h < 2; ++h)
            kfo[s][h] = (s * 16 + l15) * 64 +
                        (((h * 64 + quad * 16) ^ ((l15 & 7) << 4)) >> 1);
#pragma unroll
    for (int p2 = 0; p2 < 2; ++p2)
#pragma unroll
        for (int tt = 0; tt < 4; ++tt) {
            int d = tt * 16 + l15;
            int c = (p2 * 64 + (quad >> 1) * 32 + (quad & 1) * 16) ^ ((l15 & 7) << 4);
            vfo[p2][tt] = d * 64 + (c >> 1);
        }

    const f32x4 vzero = {0.f, 0.f, 0.f, 0.f};
    f32x4 o[4]; float l[4];
#pragma unroll
    for (int rr = 0; rr < 4; ++rr) { o[rr] = vzero; l[rr] = 0.f; }

    int nIter = (b0 + 7) >> 2;             // T = b0+4 staged subtiles
    __hip_bfloat16* Pw = &P[w][0];

    bf16x8 paP[2];          // prev-chunk P fragments (deferred PV)
    bf16x8 vfP[2][4];       // prev-chunk V fragments

    stage(0, 0);
    for (int ci = 0; ci < nIter; ++ci) {
        int cb = ci & 1;
        if (ci > 0) asm volatile("s_barrier" ::: "memory");      // buf cb^1 free
        if (ci + 1 < nIter) {
            stage(ci + 1, cb ^ 1);
            asm volatile("s_waitcnt vmcnt(4)" ::: "memory");     // chunk ci landed
        } else {
            asm volatile("s_waitcnt vmcnt(0)" ::: "memory");
        }
        asm volatile("s_barrier" ::: "memory");                  // chunk ci visible

        bf16x8 ka[4], kb8[4];
#pragma unroll
        for (int s = 0; s < 4; ++s) {
            ka[s]  = *(const bf16x8*)&KL[cb][kfo[s][0]];
            kb8[s] = *(const bf16x8*)&KL[cb][kfo[s][1]];
        }
        // scores: D[m=q][n=key]; lane: col=key=l15, row q=quad*4+rr
        f32x4 sc[4];
        __builtin_amdgcn_s_setprio(1);
#pragma unroll
        for (int s = 0; s < 4; ++s)
            sc[s] = mfma_bf16(qb, kb8[s], mfma_bf16(qa, ka[s], vzero));
        __builtin_amdgcn_s_setprio(0);
        bf16x8 vf[2][4];
#pragma unroll
        for (int p2 = 0; p2 < 2; ++p2)
#pragma unroll
            for (int tt = 0; tt < 4; ++tt)
                vf[p2][tt] = *(const bf16x8*)&VL[cb][vfo[p2][tt]];

        // exp + mask, accumulate l, write P[q][64 keys] (stride 68)
#pragma unroll
        for (int s = 0; s < 4; ++s) {
            bool a = active(4 * ci + s);
#pragma unroll
            for (int rr = 0; rr < 4; ++rr) {
                float pv = a ? __expf(sc[s][rr]) : 0.f;
                l[rr] += pv;
                Pw[(quad * 4 + rr) * 68 + s * 16 + l15] = __float2bfloat16(pv);
            }
        }
        // deferred PV of chunk ci-1: pure-register MFMAs execute while the
        // P(ci) writes drain -- hides the LDS round-trip latency.
        if (ci > 0) {
            __builtin_amdgcn_s_setprio(1);
#pragma unroll
            for (int p2 = 0; p2 < 2; ++p2)
#pragma unroll
                for (int tt = 0; tt < 4; ++tt)
                    o[tt] = mfma_bf16(paP[p2], vfP[p2][tt], o[tt]);
            __builtin_amdgcn_s_setprio(0);
        }
        asm volatile("s_waitcnt lgkmcnt(0)" ::: "memory");       // P(ci) visible
        bf16x8 pa[2];
#pragma unroll
        for (int p2 = 0; p2 < 2; ++p2) {
            union { bf16x4 h[2]; bf16x8 v; } u;
            u.h[0] = *(const bf16x4*)(Pw + l15 * 68 + p2 * 32 + quad * 8);
            u.h[1] = *(const bf16x4*)(Pw + l15 * 68 + p2 * 32 + quad * 8 + 4);
            pa[p2] = u.v;
        }
        // no drain: pa consumed next iteration (compiler emits counted wait)
#pragma unroll
        for (int p2 = 0; p2 < 2; ++p2) {
            paP[p2] = pa[p2];
#pragma unroll
            for (int tt = 0; tt < 4; ++tt) vfP[p2][tt] = vf[p2][tt];
        }
    }
    // final PV for the last chunk
    asm volatile("s_waitcnt lgkmcnt(0)" ::: "memory");
    __builtin_amdgcn_s_setprio(1);
#pragma unroll
    for (int p2 = 0; p2 < 2; ++p2)
#pragma unroll
        for (int tt = 0; tt < 4; ++tt)
            o[tt] = mfma_bf16(paP[p2], vfP[p2][tt], o[tt]);
    __builtin_amdgcn_s_setprio(0);

    // epilogue: per-wave, direct write (no merge needed)
    int b = bh / 12, h = bh - b * 12;
    int seqbase = qblk * 16;
#pragma unroll
    for (int rr = 0; rr < 4; ++rr) {
        float lr = l[rr];
#pragma unroll
        for (int msk = 1; msk < 16; msk <<= 1) lr += __shfl_xor(lr, msk, 16);
        float inv = 1.f / lr;
        long row = b * 2048 + seqbase + quad * 4 + rr;
#pragma unroll
        for (int tt = 0; tt < 4; ++tt)
            out[row * 768 + h * 64 + tt * 16 + l15] = __float2bfloat16(o[tt][rr] * inv);
    }
}

// ---------------- 128xTN bf16 GEMM, 2 LDS buffers.
// R21: L3-traffic model (staging bytes = MNK*2*(1/128+1/TN) at ~10.4 TB/s
// Infinity-Cache ceiling) + XCD-aware bijective swizzle: lin = bx + 32*by;
// bm = 4*(lin&7) + (slot&3); bn = slot>>2 -- each XCD owns 4 contiguous bm
// for ALL bn, A-tiles L2-resident, B fetched once per XCD. 288.5->280.6.
// R22: apply the same recipe to mlp2 (was TN=64 split-K=2 = 452MB, the
// worst remaining geometry): TN=128 + split-K=4 keeps 768 blocks (3/CU,
// mlp1's proven occupancy) at 302MB raw / ~compulsory with swizzle.
// Depth-1 pipeline: stage(i+1) after top barrier, vmcnt(NINST), barrier,
// XOR-swizzled conflict-free ds_read_b128.
// MODE 1: Cf = mods[gate]*acc + resid   (attn proj + gate + residual)
// MODE 2: Cb = bf16(fast_gelu(acc + bias))   (mlp1)
// MODE 4: qkv + fused RoPE epilogue -> q (x0.125), k, vT bf16 (TN=64 only).
// MODE 5: split-K partial: Cb[z*M*N + row*N+col] = bf16(acc).
template <int MODE, int TN>
__global__ __launch_bounds__(TN == 128 ? 256 : 128) void k_gemm(
    const __hip_bfloat16* __restrict__ A, const __hip_bfloat16* __restrict__ W,
    float* __restrict__ Cf, __hip_bfloat16* __restrict__ Cb,
    const float* __restrict__ bias, const float* __restrict__ mods, int gateOff,
    const float* __restrict__ resid, const float* __restrict__ cosb,
    const float* __restrict__ sinb, __hip_bfloat16* __restrict__ qo,
    __hip_bfloat16* __restrict__ ko, __hip_bfloat16* __restrict__ vo,
    int M, int N, int K, int lda) {
    constexpr int NW = (TN == 128) ? 4 : 2;
    constexpr int ACH = 512 / (NW * 64);
    constexpr int BCH = (TN * 4) / (NW * 64);
    constexpr int NINST = ACH + BCH;
    constexpr int SM_SHORTS = 2 * 128 * 32 + 2 * TN * 32;
    __shared__ __align__(16) __hip_bfloat16 SM[SM_SHORTS];
    int t = threadIdx.x;
    int wave = t >> 6, lane = t & 63, l15 = lane & 15, quad = lane >> 4;
    int wr = (TN == 128) ? (wave >> 1) : wave;
    int wc = (TN == 128) ? (wave & 1) : 0;
    int sw8 = (quad ^ ((l15 >> 1) & 3)) * 8;
    // XCD-aware swizzle: each XCD owns bm in [4*xcd, 4*xcd+4) for all bn.
    int lin = (int)blockIdx.x + 32 * (int)blockIdx.y;
    int slot = lin >> 3;
    long bm = 4 * (lin & 7) + (slot & 3);
    long bn = slot >> 2;
    const __hip_bfloat16* Ab = A + bm * 128 * lda + (long)blockIdx.z * K;
    const __hip_bfloat16* Wb = W + bn * TN * lda + (long)blockIdx.z * K;

    long soffA[ACH], soffB[BCH];
#pragma unroll
    for (int cc = 0; cc < ACH; ++cc) {
        int chunk = cc * NW * 64 + t;
        int row = chunk >> 2;
        int c = (chunk & 3) ^ ((row >> 1) & 3);
        soffA[cc] = (long)row * lda + c * 8;
    }
#pragma unroll
    for (int cc = 0; cc < BCH; ++cc) {
        int chunk = cc * NW * 64 + t;
        int row = chunk >> 2;
        int c = (chunk & 3) ^ ((row >> 1) & 3);
        soffB[cc] = (long)row * lda + c * 8;
    }
    auto stage = [&](int k0, int buf) {
        char* lAc = (char*)(SM + buf * 4096);
        char* lBc = (char*)(SM + 8192 + buf * (TN * 32));
#pragma unroll
        for (int cc = 0; cc < ACH; ++cc)
            async_ld16(Ab + soffA[cc] + k0, lAc + cc * (NW * 1024) + wave * 1024);
#pragma unroll
        for (int cc = 0; cc < BCH; ++cc)
            async_ld16(Wb + soffB[cc] + k0, lBc + cc * (NW * 1024) + wave * 1024);
    };

    f32x4 acc[4][4];
#pragma unroll
    for (int i = 0; i < 4; ++i)
#pragma unroll
        for (int j = 0; j < 4; ++j) acc[i][j] = (f32x4){0.f, 0.f, 0.f, 0.f};

    int nIter = K / 32;
    stage(0, 0);
    for (int i = 0; i < nIter; ++i) {
        int cb = i & 1;
        if (i > 0) asm volatile("s_barrier" ::: "memory");   // buf !cb free
        if (i + 1 < nIter) {
            stage((i + 1) * 32, cb ^ 1);
            asm volatile("s_waitcnt vmcnt(%0)" :: "n"(NINST) : "memory");  // tile i landed
        } else {
            asm volatile("s_waitcnt vmcnt(0)" ::: "memory");
        }
        asm volatile("s_barrier" ::: "memory");              // tile i visible
        bf16x8 af[4], bfr[4];
#pragma unroll
        for (int ii = 0; ii < 4; ++ii)
            af[ii] = *(const bf16x8*)&SM[cb * 4096 + (wr * 64 + ii * 16 + l15) * 32 + sw8];
#pragma unroll
        for (int j = 0; j < 4; ++j)
            bfr[j] = *(const bf16x8*)&SM[8192 + cb * (TN * 32) + (wc * 64 + j * 16 + l15) * 32 + sw8];
#pragma unroll
        for (int ii = 0; ii < 4; ++ii)
#pragma unroll
            for (int j = 0; j < 4; ++j)
                acc[ii][j] = mfma_bf16(af[ii], bfr[j], acc[ii][j]);
    }

    if (MODE == 4) {
        static_assert(MODE != 4 || TN == 64, "MODE4 requires TN=64");
        int th = (int)bn / 12, h = (int)bn % 12;   // head-col = bn (TN=64)
        int sbase = ((int)bm * 128) & 2047;
        int b = ((int)bm * 128) >> 11;
        long bh_ = (long)b * 12 + h;
        if (th == 2) {
            // vT: RoPE into LDS [64 d][132 s] transpose tile (reuses staging
            // SMEM), then coalesced 256B dword rows. Replaces 2B/4KB-stride
            // scattered stores (64 txns/inst) with 1-txn coalesced stores.
            __syncthreads();
#pragma unroll
            for (int i = 0; i < 4; ++i) {
                int sl = wr * 64 + i * 16 + quad * 4;
#pragma unroll
                for (int j = 0; j < 2; ++j) {
                    int dh = j * 16 + l15;
                    bf16x4 p0, p1;
#pragma unroll
                    for (int r = 0; r < 4; ++r) {
                        int s = sbase + sl + r;
                        const float* cbp = cosb + s * 64;
                        const float* sbp = sinb + s * 64;
                        float a0f = acc[i][j][r], a1f = acc[i][j + 2][r];
                        p0[r] = f2bf_s(a0f * cbp[dh] - a1f * sbp[dh]);
                        p1[r] = f2bf_s(a1f * cbp[dh + 32] + a0f * sbp[dh + 32]);
                    }
                    *(bf16x4*)(SM + dh * 132 + sl) = p0;
                    *(bf16x4*)(SM + (dh + 32) * 132 + sl) = p1;
                }
            }
            __syncthreads();
            __hip_bfloat16* dst = vo + bh_ * 64 * 2048;
#pragma unroll
            for (int dd = 0; dd < 32; ++dd) {
                int d = wr * 32 + dd;
                unsigned pv = *(const unsigned*)(SM + d * 132 + lane * 2);
                *(unsigned*)(dst + (long)d * 2048 + sbase + lane * 2) = pv;
            }
            return;
        }
        // th 0/1: q (x0.125) / k, direct stores (16-lane 32B runs)
        float qs = (th == 0) ? 0.125f : 1.f;
        __hip_bfloat16* base = (th == 0) ? qo : ko;
#pragma unroll
        for (int i = 0; i < 4; ++i) {
#pragma unroll
            for (int r = 0; r < 4; ++r) {
                int s = sbase + wr * 64 + i * 16 + quad * 4 + r;
                const float* cbp = cosb + s * 64;
                const float* sbp = sinb + s * 64;
                __hip_bfloat16* d = base + (bh_ * 2048 + s) * 64;
#pragma unroll
                for (int j = 0; j < 2; ++j) {
                    int dh = j * 16 + l15;
                    float a0f = acc[i][j][r], a1f = acc[i][j + 2][r];
                    float o0 = a0f * cbp[dh] - a1f * sbp[dh];
                    float o1 = a1f * cbp[dh + 32] + a0f * sbp[dh + 32];
                    d[dh]      = __float2bfloat16(o0 * qs);
                    d[dh + 32] = __float2bfloat16(o1 * qs);
                }
            }
        }
        return;
    }

#pragma unroll
    for (int i = 0; i < 4; ++i) {
#pragma unroll
        for (int j = 0; j < 4; ++j) {
#pragma unroll
            for (int r = 0; r < 4; ++r) {
                int row = (int)bm * 128 + wr * 64 + i * 16 + quad * 4 + r;
                int col = (int)bn * TN + wc * 64 + j * 16 + l15;
                float v = acc[i][j][r];
                long idx = (long)row * N + col;
                if (MODE == 1) {
                    Cf[idx] = mods[(row >> 11) * 4608 + gateOff + col] * v + resid[idx];
                } else if (MODE == 2) {
                    Cb[idx] = __float2bfloat16(fast_gelu(v + bias[col]));
                } else {   // MODE 5: split-K partial
                    Cb[(long)blockIdx.z * M * N + idx] = __float2bfloat16(v);
                }
            }
        }
    }
}

extern "C" void kernel_launch(void* const* d_in, const int* in_sizes, int n_in,
                              void* d_out, int out_size, void* d_ws, size_t ws_size,
                              hipStream_t stream) {
    const float* x    = (const float*)d_in[0];
    const float* c    = (const float*)d_in[1];
    const float* cosb = (const float*)d_in[2];
    const float* sinb = (const float*)d_in[3];
    // d_in[4] = mask: unused, computed analytically
    const float* n1w  = (const float*)d_in[5];
    const float* qkvw = (const float*)d_in[6];
    const float* aow  = (const float*)d_in[7];
    const float* n2w  = (const float*)d_in[8];
    const float* w1   = (const float*)d_in[9];
    const float* b1   = (const float*)d_in[10];
    const float* w2   = (const float*)d_in[11];
    const float* b2   = (const float*)d_in[12];
    const float* alw  = (const float*)d_in[13];
    const float* alb  = (const float*)d_in[14];

    char* ws = (char*)d_ws;
    size_t off = 0;
    auto alloc = [&](size_t bytes) -> void* {
        void* p = ws + off;
        off += (bytes + 255) & ~(size_t)255;
        return p;
    };
    float*          mods = (float*)alloc(2 * 4608 * 4);
    __hip_bfloat16* hbuf = (__hip_bfloat16*)alloc((size_t)4096 * 768 * 2);
    __hip_bfloat16* qb   = (__hip_bfloat16*)alloc((size_t)24 * 2048 * 64 * 2);
    __hip_bfloat16* kb   = (__hip_bfloat16*)alloc((size_t)24 * 2048 * 64 * 2);
    __hip_bfloat16* vT   = (__hip_bfloat16*)alloc((size_t)24 * 64 * 2048 * 2);
    __hip_bfloat16* abuf = (__hip_bfloat16*)alloc((size_t)4096 * 768 * 2);
    float*          x2   = (float*)alloc((size_t)4096 * 768 * 4);
    __hip_bfloat16* h2   = (__hip_bfloat16*)alloc((size_t)4096 * 768 * 2);
    __hip_bfloat16* m1   = (__hip_bfloat16*)alloc((size_t)4096 * 3072 * 2);
    __hip_bfloat16* m2p  = (__hip_bfloat16*)alloc((size_t)4 * 4096 * 768 * 2);
    __hip_bfloat16* wq   = (__hip_bfloat16*)alloc((size_t)2304 * 768 * 2);
    __hip_bfloat16* wa   = (__hip_bfloat16*)alloc((size_t)768 * 768 * 2);
    __hip_bfloat16* w1b  = (__hip_bfloat16*)alloc((size_t)3072 * 768 * 2);
    __hip_bfloat16* w2b  = (__hip_bfloat16*)alloc((size_t)768 * 3072 * 2);

    k_pre<<<27684, 256, 0, stream>>>(qkvw, wq, 2304 * 768, aow, wa, 768 * 768,
                                     w1, w1b, 3072 * 768, w2, w2b, 768 * 3072,
                                     c, alw, alb, mods);
    k_ln_mod<<<4096, 64, 0, stream>>>(x, n1w, mods, 0, 768, hbuf);
    // qkv GEMM + fused RoPE -> q, k, vT (64-tile: 1152 blocks, XCD-swizzled)
    k_gemm<4, 64><<<dim3(32, 36), 128, 0, stream>>>(hbuf, wq, nullptr, nullptr, nullptr, nullptr, 0,
                                                    nullptr, cosb, sinb, qb, kb, vT,
                                                    4096, 2304, 768, 768);
    k_attn<<<768, 256, 0, stream>>>(qb, kb, vT, abuf);
    k_gemm<1, 64><<<dim3(32, 12), 128, 0, stream>>>(abuf, wa, x2, nullptr, nullptr, mods, 1536,
                                                    x, nullptr, nullptr, nullptr, nullptr, nullptr,
                                                    4096, 768, 768, 768);
    k_ln_mod<<<4096, 64, 0, stream>>>(x2, n2w, mods, 2304, 3072, h2);
    // mlp1: 128x128 (768 blocks = 3/CU, lowest-traffic tiling, XCD-swizzled)
    k_gemm<2, 128><<<dim3(32, 24), 256, 0, stream>>>(h2, w1b, nullptr, m1, b1, nullptr, 0,
                                                     nullptr, nullptr, nullptr, nullptr, nullptr, nullptr,
                                                     4096, 3072, 768, 768);
    // mlp2: TN=128 + split-K=4 (768 blocks = 3/CU, 302MB raw vs TN=64's 452)
    k_gemm<5, 128><<<dim3(32, 6, 4), 256, 0, stream>>>(m1, w2b, nullptr, m2p, nullptr, nullptr, 0,
                                                       nullptr, nullptr, nullptr, nullptr, nullptr, nullptr,
                                                       4096, 768, 768, 3072);
    k_red<<<3072, 256, 0, stream>>>(m2p, x2, mods, b2, (float*)d_out);
}

// Round 10
// 275.369 us; speedup vs baseline: 1.0627x; 1.0128x over previous
//
#include <hip/hip_runtime.h>
#include <hip/hip_bf16.h>

#define EPS 1e-5f

typedef __attribute__((ext_vector_type(8))) short bf16x8;
typedef __attribute__((ext_vector_type(4))) short bf16x4;
typedef __attribute__((ext_vector_type(4))) float f32x4;

__device__ __forceinline__ f32x4 mfma_bf16(bf16x8 a, bf16x8 b, f32x4 c) {
    return __builtin_amdgcn_mfma_f32_16x16x32_bf16(a, b, c, 0, 0, 0);
}

__device__ __forceinline__ void async_ld16(const void* g, void* l) {
    __builtin_amdgcn_global_load_lds(
        (const __attribute__((address_space(1))) void*)g,
        (__attribute__((address_space(3))) void*)l, 16, 0, 0);
}

// fast gelu: 0.5v(1+tanh z) == v * sigmoid(2z); one v_exp + one rcp.
__device__ __forceinline__ float fast_gelu(float v) {
    float z2 = 1.5957691216057308f * (v + 0.044715f * v * v * v);
    float e = __expf(z2);
    return v * e / (e + 1.f);
}

__device__ __forceinline__ float bf2f(short s) {
    union { float f; unsigned u; } v;
    v.u = ((unsigned)(unsigned short)s) << 16;
    return v.f;
}

__device__ __forceinline__ short f2bf_s(float x) {
    union { __hip_bfloat16 h; short s; } cv;
    cv.h = __float2bfloat16(x);
    return cv.s;
}

// 8-wide f32 -> bf16 convert (32B read, 16B write)
__device__ __forceinline__ void cvt8(const float* __restrict__ src,
                                     __hip_bfloat16* __restrict__ dst) {
    float4 v0 = *(const float4*)src;
    float4 v1 = *(const float4*)(src + 4);
    bf16x8 r;
    r[0] = f2bf_s(v0.x); r[1] = f2bf_s(v0.y); r[2] = f2bf_s(v0.z); r[3] = f2bf_s(v0.w);
    r[4] = f2bf_s(v1.x); r[5] = f2bf_s(v1.y); r[6] = f2bf_s(v1.z); r[7] = f2bf_s(v1.w);
    *(bf16x8*)dst = r;
}

// ---------------- merged pre-work: f32->bf16 weight convert (blocks 0..3455,
// 8 elems/thread, vectorized: R23 dispatch-overhead fix, was 27648 scalar
// blocks) + adaLN mods[b][i] = c[b].adaLN_w[i] + adaLN_b[i] (last 36 blocks)
__global__ void k_pre(const float* __restrict__ a, __hip_bfloat16* __restrict__ oa, int na,
                      const float* __restrict__ b, __hip_bfloat16* __restrict__ ob, int nb,
                      const float* __restrict__ c, __hip_bfloat16* __restrict__ oc, int nc,
                      const float* __restrict__ d, __hip_bfloat16* __restrict__ od, int nd,
                      const float* __restrict__ cond, const float* __restrict__ alw,
                      const float* __restrict__ alb, float* __restrict__ mods) {
    if (blockIdx.x >= 3456) {
        int i = (blockIdx.x - 3456) * 256 + threadIdx.x;   // 0..9215
        int bb = i / 4608, row = i - bb * 4608;
        const float4* cv = (const float4*)(cond + bb * 128);
        const float4* wv = (const float4*)(alw + (long)row * 128);
        float acc = 0.f;
#pragma unroll
        for (int k = 0; k < 32; ++k) {
            float4 x = cv[k], y = wv[k];
            acc += x.x * y.x + x.y * y.y + x.z * y.z + x.w * y.w;
        }
        mods[i] = acc + alb[row];
        return;
    }
    long i = ((long)blockIdx.x * 256 + threadIdx.x) * 8;   // all sizes %8==0
    if (i < na) { cvt8(a + i, oa + i); return; }
    i -= na;
    if (i < nb) { cvt8(b + i, ob + i); return; }
    i -= nb;
    if (i < nc) { cvt8(c + i, oc + i); return; }
    i -= nc;
    if (i < nd) cvt8(d + i, od + i);
}

// ---------------- fused LayerNorm + adaLN modulate, 1 wave per token,
// 4 tokens per 256-thread block (R23: was 4096 blocks x 64 threads).
__global__ __launch_bounds__(256) void k_ln_mod(
        const float* __restrict__ x, const float* __restrict__ w,
        const float* __restrict__ mods, int shiftOff, int scaleOff,
        __hip_bfloat16* __restrict__ out) {
    int token = blockIdx.x * 4 + (threadIdx.x >> 6);    // 0..4095
    int lane = threadIdx.x & 63;
    const float4* xr = (const float4*)(x + (long)token * 768);
    float4 v0 = xr[lane], v1 = xr[lane + 64], v2 = xr[lane + 128];
    float s  = v0.x + v0.y + v0.z + v0.w + v1.x + v1.y + v1.z + v1.w + v2.x + v2.y + v2.z + v2.w;
    float ss = v0.x*v0.x + v0.y*v0.y + v0.z*v0.z + v0.w*v0.w
             + v1.x*v1.x + v1.y*v1.y + v1.z*v1.z + v1.w*v1.w
             + v2.x*v2.x + v2.y*v2.y + v2.z*v2.z + v2.w*v2.w;
#pragma unroll
    for (int m = 32; m >= 1; m >>= 1) { s += __shfl_xor(s, m); ss += __shfl_xor(ss, m); }
    float mu = s * (1.f / 768.f);
    float var = ss * (1.f / 768.f) - mu * mu;
    float rs = rsqrtf(var + EPS);
    int b = token >> 11;
    const float* sh = mods + b * 4608 + shiftOff;
    const float* sc = mods + b * 4608 + scaleOff;
    __hip_bfloat16* o = out + (long)token * 768;
    float4 vv[3] = {v0, v1, v2};
#pragma unroll
    for (int kk = 0; kk < 3; ++kk) {
        int cbase = (lane + 64 * kk) * 4;
        const float* p = (const float*)&vv[kk];
#pragma unroll
        for (int j = 0; j < 4; ++j) {
            int col = cbase + j;
            float hv = (p[j] - mu) * rs * w[col] * (1.f + sc[col]) + sh[col];
            o[col] = __float2bfloat16(hv);
        }
    }
}

// ---------------- split-K reduce + mlp2 epilogue (4 partials), grid-stride
// (R23: 1536 blocks): out = x2 + gate*(p0+p1+p2+p3 + bias).
__global__ __launch_bounds__(256) void k_red(
        const __hip_bfloat16* __restrict__ p, const float* __restrict__ x2,
        const float* __restrict__ mods, const float* __restrict__ bias,
        float* __restrict__ out) {
    for (long tt = (long)blockIdx.x * 256 + threadIdx.x; tt < 786432;
         tt += (long)gridDim.x * 256) {
        long base = tt * 4;
        int col = (int)(base % 768);
        int row = (int)(base / 768);
        int b = row >> 11;
        float sx = 0.f, sy = 0.f, sz = 0.f, sw = 0.f;
#pragma unroll
        for (int z = 0; z < 4; ++z) {
            short4 a = *(const short4*)(p + (long)z * 3145728 + base);
            sx += bf2f(a.x); sy += bf2f(a.y); sz += bf2f(a.z); sw += bf2f(a.w);
        }
        float4 xr = *(const float4*)(x2 + base);
        float4 gt = *(const float4*)(mods + b * 4608 + 3840 + col);
        float4 bs = *(const float4*)(bias + col);
        float4 o;
        o.x = xr.x + gt.x * (sx + bs.x);
        o.y = xr.y + gt.y * (sy + bs.y);
        o.z = xr.z + gt.z * (sz + bs.z);
        o.w = xr.w + gt.w * (sw + bs.w);
        *(float4*)(out + base) = o;
    }
}

// ---------------- block-sparse flash attention, no-max softmax.
// R18: coalesced LDS staging of K/V (shared across 4 waves/workgroup) cut
// scattered-gather txns ~10x -> 56 -> ~36us. R19 deferred-PV pipeline:
// neutral (kept). Structure: workgroup = 4 q-blocks sharing a prefix,
// w=0..3 <-> (fl,blk) in {(0,b0),(1,b0),(0,b0+1),(1,b0+1)}; K/V chunks
// staged via coalesced global_load_lds (dbuf, vmcnt(4)), XOR-swizzled via
// pre-swizzled GLOBAL source (LDS dest linear, m104/m173); conflict-free
// ds_read_b128 fragments. Per-wave act masks; tail subtiles masked p=0.
__global__ __launch_bounds__(256) void k_attn(
    const __hip_bfloat16* __restrict__ q, const __hip_bfloat16* __restrict__ k,
    const __hip_bfloat16* __restrict__ vT, __hip_bfloat16* __restrict__ out) {
    __shared__ __hip_bfloat16 KL[2][64 * 64];   // [buf][key(64)][dim(64)] swizzled
    __shared__ __hip_bfloat16 VL[2][64 * 64];   // [buf][dim(64)][lkey(64)] swizzled
    __shared__ __hip_bfloat16 P[4][16 * 68];    // per-wave P tile
    int tid = threadIdx.x;
    int w = tid >> 6, lane = tid & 63, l15 = lane & 15, quad = lane >> 4;
    int idx = blockIdx.x;                  // 0..767
    int bh = idx % 24;                     // fastest: spreads across XCDs
    int gi = idx / 24;                     // 0..31
    int b0 = 62 - 2 * gi;                  // longest prefix first
    int fl = w & 1, blk = b0 + (w >> 1);
    int qblk = fl * 64 + blk;

    const __hip_bfloat16* Q = q + ((long)bh * 2048 + qblk * 16) * 64;
    bf16x8 qa = *(const bf16x8*)(Q + l15 * 64 + quad * 8);
    bf16x8 qb = *(const bf16x8*)(Q + l15 * 64 + 32 + quad * 8);
    const __hip_bfloat16* K = k + (long)bh * 2048 * 64;
    const __hip_bfloat16* V = vT + (long)bh * 64 * 2048;

    // staged subtile t -> global key base (clamped to 0 when out of range)
    auto kbase = [&](int t) -> int {
        if (t < b0 + 2) return 1024 + t * 16;
        if (t == b0 + 2) return b0 * 16;
        if (t == b0 + 3) return (b0 + 1) * 16;
        return 0;
    };
    // per-wave subtile activity (wave-uniform)
    auto active = [&](int t) -> bool {
        if (w == 0) return t < b0 || t == b0 + 2;
        if (w == 1) return t < b0 + 1;
        if (w == 2) return t < b0 + 1 || t == b0 + 3;
        return t < b0 + 2;
    };

    // staging decode constants (per thread: 2 K instrs + 2 V instrs)
    int kkr[2], kbs[2], vsi[2], vki[2];
#pragma unroll
    for (int i = 0; i < 2; ++i) {
        int o = i * 4096 + tid * 16;
        kkr[i] = o >> 7;
        int b = o & 127;
        kbs[i] = b ^ ((kkr[i] & 7) << 4);
        int lk2 = b ^ ((kkr[i] & 7) << 4);   // same row index for V decode
        vsi[i] = lk2 >> 5;
        vki[i] = (lk2 & 31) >> 1;
    }
    auto stage = [&](int ci, int buf) {
#pragma unroll
        for (int i = 0; i < 2; ++i) {
            int gk = kbase(4 * ci + (kkr[i] >> 4)) + (kkr[i] & 15);
            async_ld16(K + (long)gk * 64 + (kbs[i] >> 1),
                       (char*)&KL[buf][0] + i * 4096 + tid * 16);
        }
#pragma unroll
        for (int i = 0; i < 2; ++i) {
            int gk = kbase(4 * ci + vsi[i]) + vki[i];
            async_ld16(V + (long)kkr[i] * 2048 + gk,
                       (char*)&VL[buf][0] + i * 4096 + tid * 16);
        }
    };

    // fragment LDS offsets (shorts), swizzle matches staging
    int kfo[4][2], vfo[2][4];
#pragma unroll
    for (int s = 0; s < 4; ++s)
#pragma unroll
        for (int h = 0; h < 2; ++h)
            kfo[s][h] = (s * 16 + l15) * 64 +
                        (((h * 64 + quad * 16) ^ ((l15 & 7) << 4)) >> 1);
#pragma unroll
    for (int p2 = 0; p2 < 2; ++p2)
#pragma unroll
        for (int tt = 0; tt < 4; ++tt) {
            int d = tt * 16 + l15;
            int c = (p2 * 64 + (quad >> 1) * 32 + (quad & 1) * 16) ^ ((l15 & 7) << 4);
            vfo[p2][tt] = d * 64 + (c >> 1);
        }

    const f32x4 vzero = {0.f, 0.f, 0.f, 0.f};
    f32x4 o[4]; float l[4];
#pragma unroll
    for (int rr = 0; rr < 4; ++rr) { o[rr] = vzero; l[rr] = 0.f; }

    int nIter = (b0 + 7) >> 2;             // T = b0+4 staged subtiles
    __hip_bfloat16* Pw = &P[w][0];

    bf16x8 paP[2];          // prev-chunk P fragments (deferred PV)
    bf16x8 vfP[2][4];       // prev-chunk V fragments

    stage(0, 0);
    for (int ci = 0; ci < nIter; ++ci) {
        int cb = ci & 1;
        if (ci > 0) asm volatile("s_barrier" ::: "memory");      // buf cb^1 free
        if (ci + 1 < nIter) {
            stage(ci + 1, cb ^ 1);
            asm volatile("s_waitcnt vmcnt(4)" ::: "memory");     // chunk ci landed
        } else {
            asm volatile("s_waitcnt vmcnt(0)" ::: "memory");
        }
        asm volatile("s_barrier" ::: "memory");                  // chunk ci visible

        bf16x8 ka[4], kb8[4];
#pragma unroll
        for (int s = 0; s < 4; ++s) {
            ka[s]  = *(const bf16x8*)&KL[cb][kfo[s][0]];
            kb8[s] = *(const bf16x8*)&KL[cb][kfo[s][1]];
        }
        // scores: D[m=q][n=key]; lane: col=key=l15, row q=quad*4+rr
        f32x4 sc[4];
        __builtin_amdgcn_s_setprio(1);
#pragma unroll
        for (int s = 0; s < 4; ++s)
            sc[s] = mfma_bf16(qb, kb8[s], mfma_bf16(qa, ka[s], vzero));
        __builtin_amdgcn_s_setprio(0);
        bf16x8 vf[2][4];
#pragma unroll
        for (int p2 = 0; p2 < 2; ++p2)
#pragma unroll
            for (int tt = 0; tt < 4; ++tt)
                vf[p2][tt] = *(const bf16x8*)&VL[cb][vfo[p2][tt]];

        // exp + mask, accumulate l, write P[q][64 keys] (stride 68)
#pragma unroll
        for (int s = 0; s < 4; ++s) {
            bool a = active(4 * ci + s);
#pragma unroll
            for (int rr = 0; rr < 4; ++rr) {
                float pv = a ? __expf(sc[s][rr]) : 0.f;
                l[rr] += pv;
                Pw[(quad * 4 + rr) * 68 + s * 16 + l15] = __float2bfloat16(pv);
            }
        }
        // deferred PV of chunk ci-1: pure-register MFMAs execute while the
        // P(ci) writes drain -- hides the LDS round-trip latency.
        if (ci > 0) {
            __builtin_amdgcn_s_setprio(1);
#pragma unroll
            for (int p2 = 0; p2 < 2; ++p2)
#pragma unroll
                for (int tt = 0; tt < 4; ++tt)
                    o[tt] = mfma_bf16(paP[p2], vfP[p2][tt], o[tt]);
            __builtin_amdgcn_s_setprio(0);
        }
        asm volatile("s_waitcnt lgkmcnt(0)" ::: "memory");       // P(ci) visible
        bf16x8 pa[2];
#pragma unroll
        for (int p2 = 0; p2 < 2; ++p2) {
            union { bf16x4 h[2]; bf16x8 v; } u;
            u.h[0] = *(const bf16x4*)(Pw + l15 * 68 + p2 * 32 + quad * 8);
            u.h[1] = *(const bf16x4*)(Pw + l15 * 68 + p2 * 32 + quad * 8 + 4);
            pa[p2] = u.v;
        }
        // no drain: pa consumed next iteration (compiler emits counted wait)
#pragma unroll
        for (int p2 = 0; p2 < 2; ++p2) {
            paP[p2] = pa[p2];
#pragma unroll
            for (int tt = 0; tt < 4; ++tt) vfP[p2][tt] = vf[p2][tt];
        }
    }
    // final PV for the last chunk
    asm volatile("s_waitcnt lgkmcnt(0)" ::: "memory");
    __builtin_amdgcn_s_setprio(1);
#pragma unroll
    for (int p2 = 0; p2 < 2; ++p2)
#pragma unroll
        for (int tt = 0; tt < 4; ++tt)
            o[tt] = mfma_bf16(paP[p2], vfP[p2][tt], o[tt]);
    __builtin_amdgcn_s_setprio(0);

    // epilogue: per-wave, direct write (no merge needed)
    int b = bh / 12, h = bh - b * 12;
    int seqbase = qblk * 16;
#pragma unroll
    for (int rr = 0; rr < 4; ++rr) {
        float lr = l[rr];
#pragma unroll
        for (int msk = 1; msk < 16; msk <<= 1) lr += __shfl_xor(lr, msk, 16);
        float inv = 1.f / lr;
        long row = b * 2048 + seqbase + quad * 4 + rr;
#pragma unroll
        for (int tt = 0; tt < 4; ++tt)
            out[row * 768 + h * 64 + tt * 16 + l15] = __float2bfloat16(o[tt][rr] * inv);
    }
}

// ---------------- 128xTN bf16 GEMM, 2 LDS buffers.
// R21: L3-traffic model (staging bytes = MNK*2*(1/128+1/TN) at ~10.4 TB/s
// Infinity-Cache ceiling) + XCD-aware bijective swizzle: lin = bx + 32*by;
// bm = 4*(lin&7) + (slot&3); bn = slot>>2 -- each XCD owns 4 contiguous bm
// for ALL bn, A-tiles L2-resident, B fetched once per XCD. 288.5->280.6.
// R22: mlp2 TN=128 + split-K=4 (768 blocks, 302MB raw). 280.6->278.9.
// Depth-1 pipeline: stage(i+1) after top barrier, vmcnt(NINST), barrier,
// XOR-swizzled conflict-free ds_read_b128.
// MODE 1: Cf = mods[gate]*acc + resid   (attn proj + gate + residual)
// MODE 2: Cb = bf16(fast_gelu(acc + bias))   (mlp1)
// MODE 4: qkv + fused RoPE epilogue -> q (x0.125), k, vT bf16 (TN=64 only).
// MODE 5: split-K partial: Cb[z*M*N + row*N+col] = bf16(acc).
template <int MODE, int TN>
__global__ __launch_bounds__(TN == 128 ? 256 : 128) void k_gemm(
    const __hip_bfloat16* __restrict__ A, const __hip_bfloat16* __restrict__ W,
    float* __restrict__ Cf, __hip_bfloat16* __restrict__ Cb,
    const float* __restrict__ bias, const float* __restrict__ mods, int gateOff,
    const float* __restrict__ resid, const float* __restrict__ cosb,
    const float* __restrict__ sinb, __hip_bfloat16* __restrict__ qo,
    __hip_bfloat16* __restrict__ ko, __hip_bfloat16* __restrict__ vo,
    int M, int N, int K, int lda) {
    constexpr int NW = (TN == 128) ? 4 : 2;
    constexpr int ACH = 512 / (NW * 64);
    constexpr int BCH = (TN * 4) / (NW * 64);
    constexpr int NINST = ACH + BCH;
    constexpr int SM_SHORTS = 2 * 128 * 32 + 2 * TN * 32;
    __shared__ __align__(16) __hip_bfloat16 SM[SM_SHORTS];
    int t = threadIdx.x;
    int wave = t >> 6, lane = t & 63, l15 = lane & 15, quad = lane >> 4;
    int wr = (TN == 128) ? (wave >> 1) : wave;
    int wc = (TN == 128) ? (wave & 1) : 0;
    int sw8 = (quad ^ ((l15 >> 1) & 3)) * 8;
    // XCD-aware swizzle: each XCD owns bm in [4*xcd, 4*xcd+4) for all bn.
    int lin = (int)blockIdx.x + 32 * (int)blockIdx.y;
    int slot = lin >> 3;
    long bm = 4 * (lin & 7) + (slot & 3);
    long bn = slot >> 2;
    const __hip_bfloat16* Ab = A + bm * 128 * lda + (long)blockIdx.z * K;
    const __hip_bfloat16* Wb = W + bn * TN * lda + (long)blockIdx.z * K;

    long soffA[ACH], soffB[BCH];
#pragma unroll
    for (int cc = 0; cc < ACH; ++cc) {
        int chunk = cc * NW * 64 + t;
        int row = chunk >> 2;
        int c = (chunk & 3) ^ ((row >> 1) & 3);
        soffA[cc] = (long)row * lda + c * 8;
    }
#pragma unroll
    for (int cc = 0; cc < BCH; ++cc) {
        int chunk = cc * NW * 64 + t;
        int row = chunk >> 2;
        int c = (chunk & 3) ^ ((row >> 1) & 3);
        soffB[cc] = (long)row * lda + c * 8;
    }
    auto stage = [&](int k0, int buf) {
        char* lAc = (char*)(SM + buf * 4096);
        char* lBc = (char*)(SM + 8192 + buf * (TN * 32));
#pragma unroll
        for (int cc = 0; cc < ACH; ++cc)
            async_ld16(Ab + soffA[cc] + k0, lAc + cc * (NW * 1024) + wave * 1024);
#pragma unroll
        for (int cc = 0; cc < BCH; ++cc)
            async_ld16(Wb + soffB[cc] + k0, lBc + cc * (NW * 1024) + wave * 1024);
    };

    f32x4 acc[4][4];
#pragma unroll
    for (int i = 0; i < 4; ++i)
#pragma unroll
        for (int j = 0; j < 4; ++j) acc[i][j] = (f32x4){0.f, 0.f, 0.f, 0.f};

    int nIter = K / 32;
    stage(0, 0);
    for (int i = 0; i < nIter; ++i) {
        int cb = i & 1;
        if (i > 0) asm volatile("s_barrier" ::: "memory");   // buf !cb free
        if (i + 1 < nIter) {
            stage((i + 1) * 32, cb ^ 1);
            asm volatile("s_waitcnt vmcnt(%0)" :: "n"(NINST) : "memory");  // tile i landed
        } else {
            asm volatile("s_waitcnt vmcnt(0)" ::: "memory");
        }
        asm volatile("s_barrier" ::: "memory");              // tile i visible
        bf16x8 af[4], bfr[4];
#pragma unroll
        for (int ii = 0; ii < 4; ++ii)
            af[ii] = *(const bf16x8*)&SM[cb * 4096 + (wr * 64 + ii * 16 + l15) * 32 + sw8];
#pragma unroll
        for (int j = 0; j < 4; ++j)
            bfr[j] = *(const bf16x8*)&SM[8192 + cb * (TN * 32) + (wc * 64 + j * 16 + l15) * 32 + sw8];
#pragma unroll
        for (int ii = 0; ii < 4; ++ii)
#pragma unroll
            for (int j = 0; j < 4; ++j)
                acc[ii][j] = mfma_bf16(af[ii], bfr[j], acc[ii][j]);
    }

    if (MODE == 4) {
        static_assert(MODE != 4 || TN == 64, "MODE4 requires TN=64");
        int th = (int)bn / 12, h = (int)bn % 12;   // head-col = bn (TN=64)
        int sbase = ((int)bm * 128) & 2047;
        int b = ((int)bm * 128) >> 11;
        long bh_ = (long)b * 12 + h;
        if (th == 2) {
            // vT: RoPE into LDS [64 d][132 s] transpose tile (reuses staging
            // SMEM), then coalesced 256B dword rows. Replaces 2B/4KB-stride
            // scattered stores (64 txns/inst) with 1-txn coalesced stores.
            __syncthreads();
#pragma unroll
            for (int i = 0; i < 4; ++i) {
                int sl = wr * 64 + i * 16 + quad * 4;
#pragma unroll
                for (int j = 0; j < 2; ++j) {
                    int dh = j * 16 + l15;
                    bf16x4 p0, p1;
#pragma unroll
                    for (int r = 0; r < 4; ++r) {
                        int s = sbase + sl + r;
                        const float* cbp = cosb + s * 64;
                        const float* sbp = sinb + s * 64;
                        float a0f = acc[i][j][r], a1f = acc[i][j + 2][r];
                        p0[r] = f2bf_s(a0f * cbp[dh] - a1f * sbp[dh]);
                        p1[r] = f2bf_s(a1f * cbp[dh + 32] + a0f * sbp[dh + 32]);
                    }
                    *(bf16x4*)(SM + dh * 132 + sl) = p0;
                    *(bf16x4*)(SM + (dh + 32) * 132 + sl) = p1;
                }
            }
            __syncthreads();
            __hip_bfloat16* dst = vo + bh_ * 64 * 2048;
#pragma unroll
            for (int dd = 0; dd < 32; ++dd) {
                int d = wr * 32 + dd;
                unsigned pv = *(const unsigned*)(SM + d * 132 + lane * 2);
                *(unsigned*)(dst + (long)d * 2048 + sbase + lane * 2) = pv;
            }
            return;
        }
        // th 0/1: q (x0.125) / k, direct stores (16-lane 32B runs)
        float qs = (th == 0) ? 0.125f : 1.f;
        __hip_bfloat16* base = (th == 0) ? qo : ko;
#pragma unroll
        for (int i = 0; i < 4; ++i) {
#pragma unroll
            for (int r = 0; r < 4; ++r) {
                int s = sbase + wr * 64 + i * 16 + quad * 4 + r;
                const float* cbp = cosb + s * 64;
                const float* sbp = sinb + s * 64;
                __hip_bfloat16* d = base + (bh_ * 2048 + s) * 64;
#pragma unroll
                for (int j = 0; j < 2; ++j) {
                    int dh = j * 16 + l15;
                    float a0f = acc[i][j][r], a1f = acc[i][j + 2][r];
                    float o0 = a0f * cbp[dh] - a1f * sbp[dh];
                    float o1 = a1f * cbp[dh + 32] + a0f * sbp[dh + 32];
                    d[dh]      = __float2bfloat16(o0 * qs);
                    d[dh + 32] = __float2bfloat16(o1 * qs);
                }
            }
        }
        return;
    }

#pragma unroll
    for (int i = 0; i < 4; ++i) {
#pragma unroll
        for (int j = 0; j < 4; ++j) {
#pragma unroll
            for (int r = 0; r < 4; ++r) {
                int row = (int)bm * 128 + wr * 64 + i * 16 + quad * 4 + r;
                int col = (int)bn * TN + wc * 64 + j * 16 + l15;
                float v = acc[i][j][r];
                long idx = (long)row * N + col;
                if (MODE == 1) {
                    Cf[idx] = mods[(row >> 11) * 4608 + gateOff + col] * v + resid[idx];
                } else if (MODE == 2) {
                    Cb[idx] = __float2bfloat16(fast_gelu(v + bias[col]));
                } else {   // MODE 5: split-K partial
                    Cb[(long)blockIdx.z * M * N + idx] = __float2bfloat16(v);
                }
            }
        }
    }
}

extern "C" void kernel_launch(void* const* d_in, const int* in_sizes, int n_in,
                              void* d_out, int out_size, void* d_ws, size_t ws_size,
                              hipStream_t stream) {
    const float* x    = (const float*)d_in[0];
    const float* c    = (const float*)d_in[1];
    const float* cosb = (const float*)d_in[2];
    const float* sinb = (const float*)d_in[3];
    // d_in[4] = mask: unused, computed analytically
    const float* n1w  = (const float*)d_in[5];
    const float* qkvw = (const float*)d_in[6];
    const float* aow  = (const float*)d_in[7];
    const float* n2w  = (const float*)d_in[8];
    const float* w1   = (const float*)d_in[9];
    const float* b1   = (const float*)d_in[10];
    const float* w2   = (const float*)d_in[11];
    const float* b2   = (const float*)d_in[12];
    const float* alw  = (const float*)d_in[13];
    const float* alb  = (const float*)d_in[14];

    char* ws = (char*)d_ws;
    size_t off = 0;
    auto alloc = [&](size_t bytes) -> void* {
        void* p = ws + off;
        off += (bytes + 255) & ~(size_t)255;
        return p;
    };
    float*          mods = (float*)alloc(2 * 4608 * 4);
    __hip_bfloat16* hbuf = (__hip_bfloat16*)alloc((size_t)4096 * 768 * 2);
    __hip_bfloat16* qb   = (__hip_bfloat16*)alloc((size_t)24 * 2048 * 64 * 2);
    __hip_bfloat16* kb   = (__hip_bfloat16*)alloc((size_t)24 * 2048 * 64 * 2);
    __hip_bfloat16* vT   = (__hip_bfloat16*)alloc((size_t)24 * 64 * 2048 * 2);
    __hip_bfloat16* abuf = (__hip_bfloat16*)alloc((size_t)4096 * 768 * 2);
    float*          x2   = (float*)alloc((size_t)4096 * 768 * 4);
    __hip_bfloat16* h2   = (__hip_bfloat16*)alloc((size_t)4096 * 768 * 2);
    __hip_bfloat16* m1   = (__hip_bfloat16*)alloc((size_t)4096 * 3072 * 2);
    __hip_bfloat16* m2p  = (__hip_bfloat16*)alloc((size_t)4 * 4096 * 768 * 2);
    __hip_bfloat16* wq   = (__hip_bfloat16*)alloc((size_t)2304 * 768 * 2);
    __hip_bfloat16* wa   = (__hip_bfloat16*)alloc((size_t)768 * 768 * 2);
    __hip_bfloat16* w1b  = (__hip_bfloat16*)alloc((size_t)3072 * 768 * 2);
    __hip_bfloat16* w2b  = (__hip_bfloat16*)alloc((size_t)768 * 3072 * 2);

    // R23: vectorized convert (8/thread) -> 3456+36 blocks (was 27684)
    k_pre<<<3492, 256, 0, stream>>>(qkvw, wq, 2304 * 768, aow, wa, 768 * 768,
                                    w1, w1b, 3072 * 768, w2, w2b, 768 * 3072,
                                    c, alw, alb, mods);
    k_ln_mod<<<1024, 256, 0, stream>>>(x, n1w, mods, 0, 768, hbuf);
    // qkv GEMM + fused RoPE -> q, k, vT (64-tile: 1152 blocks, XCD-swizzled)
    k_gemm<4, 64><<<dim3(32, 36), 128, 0, stream>>>(hbuf, wq, nullptr, nullptr, nullptr, nullptr, 0,
                                                    nullptr, cosb, sinb, qb, kb, vT,
                                                    4096, 2304, 768, 768);
    k_attn<<<768, 256, 0, stream>>>(qb, kb, vT, abuf);
    k_gemm<1, 64><<<dim3(32, 12), 128, 0, stream>>>(abuf, wa, x2, nullptr, nullptr, mods, 1536,
                                                    x, nullptr, nullptr, nullptr, nullptr, nullptr,
                                                    4096, 768, 768, 768);
    k_ln_mod<<<1024, 256, 0, stream>>>(x2, n2w, mods, 2304, 3072, h2);
    // mlp1: 128x128 (768 blocks = 3/CU, lowest-traffic tiling, XCD-swizzled)
    k_gemm<2, 128><<<dim3(32, 24), 256, 0, stream>>>(h2, w1b, nullptr, m1, b1, nullptr, 0,
                                                     nullptr, nullptr, nullptr, nullptr, nullptr, nullptr,
                                                     4096, 3072, 768, 768);
    // mlp2: TN=128 + split-K=4 (768 blocks = 3/CU)
    k_gemm<5, 128><<<dim3(32, 6, 4), 256, 0, stream>>>(m1, w2b, nullptr, m2p, nullptr, nullptr, 0,
                                                       nullptr, nullptr, nullptr, nullptr, nullptr, nullptr,
                                                       4096, 768, 768, 3072);
    k_red<<<1536, 256, 0, stream>>>(m2p, x2, mods, b2, (float*)d_out);
}